// Round 6
// baseline (34.794 us; speedup 1.0000x reference)
//
#include <hip/hip_runtime.h>

#define GXD 96
#define GYD 96
#define GZD 96
#define PTS_PER_B (GXD * GYD * GZD)
#define BLOCKS_PER_B (PTS_PER_B / 256)   // 3456
#define RECSZ 48
#define BIGF 1e10f
#define GLOWER -1.2f
#define GSTEP 0.025f

// ---------- exact rotate: identical op order to validated rounds ----------
__device__ __forceinline__ void rot_inv(float qx, float qy, float qz, float qw,
                                        float dx, float dy, float dz,
                                        float& rx, float& ry, float& rz)
{
    float ux = -qx, uy = -qy, uz = -qz;
    float uvx = uy * dz - uz * dy;
    float uvy = uz * dx - ux * dz;
    float uvz = ux * dy - uy * dx;
    float t2x = uvx + qw * dx;
    float t2y = uvy + qw * dy;
    float t2z = uvz + qw * dz;
    rx = dx + 2.0f * (uy * t2z - uz * t2y);
    ry = dy + 2.0f * (uz * t2x - ux * t2z);
    rz = dz + 2.0f * (ux * t2y - uy * t2x);
}

__device__ __forceinline__ float next_up(float a) { return __uint_as_float(__float_as_uint(a) + 1u); }
__device__ __forceinline__ float next_dn(float a) { return __uint_as_float(__float_as_uint(a) - 1u); }

// smallest positive float a with fl(a/w) >= t   (w>0, t>0; start within ~3 ulp)
__device__ float exact_lo(float w, float t)
{
    float a = t * w;
    while (a / w < t)            a = next_up(a);
    while (next_dn(a) / w >= t)  a = next_dn(a);
    return a;
}

// largest positive float a with fl(a/w) <= L
__device__ float exact_hi(float w, float L)
{
    float a = L * w;
    while (a / w > L)            a = next_dn(a);
    while (next_up(a) / w <= L)  a = next_up(a);
    return a;
}

// record layout (floats unless noted):
//  0-2  t      3-6  q(normalized)    7-9  invw=fl(1/w)
// 10-12 (S-1)f 13-15 A (exact lo)   16-18 B (exact hi)
// 19 (int) m*sdf_stride  20-22 (int) SX,SY,SZ  23 pad
// 24-26 world AABB lo    27-29 world AABB hi   30-31 pad
// 32-40 M = R^T row-major (world->local, approx rotate)
// 41-43 A - MRG_PF       44-46 B + MRG_PF      47 pad
__global__ void prep_v5(const int* __restrict__ shapes,
                        const int* __restrict__ indices,
                        const float* __restrict__ poses,
                        const float* __restrict__ widths,
                        float* __restrict__ rec,
                        int BN, int sdf_stride)
{
    int bn = blockIdx.x * blockDim.x + threadIdx.x;
    if (bn >= BN) return;
    int m = indices[bn];
    const float* pp = poses + (size_t)bn * 7;
    float tx = pp[0], ty = pp[1], tz = pp[2];
    float qx = pp[3], qy = pp[4], qz = pp[5], qw = pp[6];
    // identical op order to validated rounds -> bit-identical q
    float nrm = sqrtf(qx * qx + qy * qy + qz * qz + qw * qw);
    qx = qx / nrm; qy = qy / nrm; qz = qz / nrm; qw = qw / nrm;

    float wx = widths[bn * 3 + 0], wy = widths[bn * 3 + 1], wz = widths[bn * 3 + 2];
    int SX = shapes[m * 3 + 0], SY = shapes[m * 3 + 1], SZ = shapes[m * 3 + 2];
    float mx = (float)(SX - 1), my = (float)(SY - 1), mz = (float)(SZ - 1);

    // inside_x <=> fl(rx/w) in [0.5, mx+0.5] <=> rx in [A,B] (division monotone,
    // u-0.5 Sterbenz-exact on the decision range) — validated rounds 2-5
    float Ax = exact_lo(wx, 0.5f), Ay = exact_lo(wy, 0.5f), Az = exact_lo(wz, 0.5f);
    float Bx = exact_hi(wx, mx + 0.5f), By = exact_hi(wy, my + 0.5f), Bz = exact_hi(wz, mz + 0.5f);

    // rotation matrix R (local->world) from q; M = R^T (world->local)
    float xx = qx * qx, yy = qy * qy, zz = qz * qz;
    float xy = qx * qy, xz = qx * qz, yz = qy * qz;
    float wqx = qw * qx, wqy = qw * qy, wqz = qw * qz;
    float R00 = 1.0f - 2.0f * (yy + zz), R01 = 2.0f * (xy - wqz), R02 = 2.0f * (xz + wqy);
    float R10 = 2.0f * (xy + wqz), R11 = 1.0f - 2.0f * (xx + zz), R12 = 2.0f * (yz - wqx);
    float R20 = 2.0f * (xz - wqy), R21 = 2.0f * (yz + wqx), R22 = 1.0f - 2.0f * (xx + yy);

    // conservative world AABB of the exact local box [A,B] (validated round 4)
    float cx = 0.5f * (Ax + Bx), cy = 0.5f * (Ay + By), cz = 0.5f * (Az + Bz);
    float hx = 0.5f * (Bx - Ax), hy = 0.5f * (By - Ay), hz = 0.5f * (Bz - Az);
    const float MARG = 2e-3f;  // >> rotation/rounding error (~1e-6)
    float wcx = tx + R00 * cx + R01 * cy + R02 * cz;
    float wcy = ty + R10 * cx + R11 * cy + R12 * cz;
    float wcz = tz + R20 * cx + R21 * cy + R22 * cz;
    float ex = fabsf(R00) * hx + fabsf(R01) * hy + fabsf(R02) * hz + MARG;
    float ey = fabsf(R10) * hx + fabsf(R11) * hy + fabsf(R12) * hz + MARG;
    float ez = fabsf(R20) * hx + fabsf(R21) * hy + fabsf(R22) * hz + MARG;

    const float MRG_PF = 1e-4f;  // pre-filter margin >> 2e-6 matrix/chain divergence

    float* r = rec + (size_t)bn * RECSZ;
    r[0] = tx;  r[1] = ty;  r[2] = tz;
    r[3] = qx;  r[4] = qy;  r[5] = qz;  r[6] = qw;
    r[7] = 1.0f / wx; r[8] = 1.0f / wy; r[9] = 1.0f / wz;
    r[10] = mx; r[11] = my; r[12] = mz;
    r[13] = Ax; r[14] = Ay; r[15] = Az;
    r[16] = Bx; r[17] = By; r[18] = Bz;
    int* ri = (int*)r;
    ri[19] = m * sdf_stride;
    ri[20] = SX; ri[21] = SY; ri[22] = SZ;
    r[23] = 0.0f;
    r[24] = wcx - ex; r[25] = wcy - ey; r[26] = wcz - ez;
    r[27] = wcx + ex; r[28] = wcy + ey; r[29] = wcz + ez;
    r[30] = 0.0f; r[31] = 0.0f;
    // M = R^T rows
    r[32] = R00; r[33] = R10; r[34] = R20;
    r[35] = R01; r[36] = R11; r[37] = R21;
    r[38] = R02; r[39] = R12; r[40] = R22;
    r[41] = Ax - MRG_PF; r[42] = Ay - MRG_PF; r[43] = Az - MRG_PF;
    r[44] = Bx + MRG_PF; r[45] = By + MRG_PF; r[46] = Bz + MRG_PF;
    r[47] = 0.0f;
}

__device__ __forceinline__ float trilerp(const float* __restrict__ sd,
                                         float rx, float ry, float rz,
                                         float invwx, float invwy, float invwz,
                                         float mx, float my, float mz,
                                         int SX, int SY, int SZ)
{
    // reciprocal-mul g: affects interpolated VALUE only at ~ulp level;
    // the inside/outside decision was already made exactly via [A,B].
    float gx = rx * invwx - 0.5f;
    float gy = ry * invwy - 0.5f;
    float gz = rz * invwz - 0.5f;
    float fx = fminf(fmaxf(gx, 0.0f), mx);
    float fy = fminf(fmaxf(gy, 0.0f), my);
    float fz = fminf(fmaxf(gz, 0.0f), mz);
    int i0x = (int)fx, i0y = (int)fy, i0z = (int)fz;  // f>=0 -> trunc==floor
    float frx = fx - (float)i0x;
    float fry = fy - (float)i0y;
    float frz = fz - (float)i0z;
    int i1x = min(i0x + 1, SX - 1);
    int i1y = min(i0y + 1, SY - 1);
    int i1z = min(i0z + 1, SZ - 1);
    int b00 = (i0x * SY + i0y) * SZ;
    int b01 = (i0x * SY + i1y) * SZ;
    int b10 = (i1x * SY + i0y) * SZ;
    int b11 = (i1x * SY + i1y) * SZ;
    float v000 = sd[b00 + i0z], v001 = sd[b00 + i1z];
    float v010 = sd[b01 + i0z], v011 = sd[b01 + i1z];
    float v100 = sd[b10 + i0z], v101 = sd[b10 + i1z];
    float v110 = sd[b11 + i0z], v111 = sd[b11 + i1z];
    float c00 = v000 + frz * (v001 - v000);
    float c01 = v010 + frz * (v011 - v010);
    float c10 = v100 + frz * (v101 - v100);
    float c11 = v110 + frz * (v111 - v110);
    float c0 = c00 + fry * (c01 - c00);
    float c1 = c10 + fry * (c11 - c10);
    return c0 + frx * (c1 - c0);
}

__global__ __launch_bounds__(256) void sdf_grid_v5(
    const float* __restrict__ sdfs,
    const float* __restrict__ rec,
    float* __restrict__ out,
    int N)
{
    int pid = blockIdx.x * blockDim.x + threadIdx.x;  // z innermost
    int b = blockIdx.y;

    int z = pid % GZD;
    int y = (pid / GZD) % GYD;
    int x = pid / (GZD * GYD);

    float px = GLOWER + ((float)x + 0.5f) * GSTEP;
    float py = GLOWER + ((float)y + 0.5f) * GSTEP;
    float pz = GLOWER + ((float)z + 0.5f) * GSTEP;

    // ---- block-level conservative mask (uniform; was prep_mask kernel) ----
    int pid0 = blockIdx.x * 256;        // block spans one x-slab, <=4 y values
    int col0 = pid0 / GZD;
    int col2 = (pid0 + 255) / GZD;
    int bxi = col0 / GYD;
    float bpx  = GLOWER + ((float)bxi + 0.5f) * GSTEP;
    float bpyl = GLOWER + ((float)(col0 % GYD) + 0.5f) * GSTEP;
    float bpyh = GLOWER + ((float)(col2 % GYD) + 0.5f) * GSTEP;
    float bpzl = GLOWER + 0.5f * GSTEP;
    float bpzh = GLOWER + ((float)(GZD - 1) + 0.5f) * GSTEP;

    unsigned int msk = 0u;
    for (int n = 0; n < N; ++n) {
        const float* r = rec + (size_t)(b * N + n) * RECSZ;
        bool ok = (bpx  >= r[24]) & (bpx  <= r[27]) &
                  (bpyh >= r[25]) & (bpyl <= r[28]) &
                  (bpzh >= r[26]) & (bpzl <= r[29]);
        msk |= (ok ? 1u : 0u) << n;
    }

    float best = BIGF;

    for (int n = 0; n < N; ++n) {
        if (!((msk >> n) & 1u)) continue;  // whole block certainly outside SDF n

        const float* r = rec + (size_t)(b * N + n) * RECSZ;  // wave-uniform -> s_load
        float dx = px - r[0], dy = py - r[1], dz = pz - r[2];

        // cheap matrix rotate (approx) + margined conservative test
        float lx = r[32] * dx + r[33] * dy + r[34] * dz;
        float ly = r[35] * dx + r[36] * dy + r[37] * dz;
        float lz = r[38] * dx + r[39] * dy + r[40] * dz;
        bool maybe = (lx >= r[41]) & (lx <= r[44]) &
                     (ly >= r[42]) & (ly <= r[45]) &
                     (lz >= r[43]) & (lz <= r[46]);
        if (maybe) {
            // exact recompute: identical chain to validated rounds -> bit-identical
            float rx, ry, rz;
            rot_inv(r[3], r[4], r[5], r[6], dx, dy, dz, rx, ry, rz);
            bool inside = (rx >= r[13]) & (rx <= r[16]) &
                          (ry >= r[14]) & (ry <= r[17]) &
                          (rz >= r[15]) & (rz <= r[18]);
            if (inside) {
                const int* ri = (const int*)r;
                float v = trilerp(sdfs + ri[19], rx, ry, rz,
                                  r[7], r[8], r[9], r[10], r[11], r[12],
                                  ri[20], ri[21], ri[22]);
                best = fminf(best, v);
            }
        }
    }

    out[(size_t)b * PTS_PER_B + pid] = best;
}

// ---------------- fallback: round-0 validated monolithic kernel ----------------
__global__ __launch_bounds__(256) void sdf_grid_kernel(
    const float* __restrict__ sdfs,
    const int*   __restrict__ sdf_shapes,
    const int*   __restrict__ indices,
    const float* __restrict__ poses,
    const float* __restrict__ widths,
    float*       __restrict__ out,
    int total, int N, int sdf_stride)
{
    int idx = blockIdx.x * blockDim.x + threadIdx.x;
    if (idx >= total) return;
    int z = idx % GZD;
    int y = (idx / GZD) % GYD;
    int x = (idx / (GZD * GYD)) % GXD;
    int b = idx / (GZD * GYD * GXD);
    float px = GLOWER + ((float)x + 0.5f) * GSTEP;
    float py = GLOWER + ((float)y + 0.5f) * GSTEP;
    float pz = GLOWER + ((float)z + 0.5f) * GSTEP;
    float best = BIGF;
    for (int n = 0; n < N; ++n) {
        int bn = b * N + n;
        int m  = indices[bn];
        const float* pp = poses + (size_t)bn * 7;
        float tx = pp[0], ty = pp[1], tz = pp[2];
        float qx = pp[3], qy = pp[4], qz = pp[5], qw = pp[6];
        float nrm = sqrtf(qx * qx + qy * qy + qz * qz + qw * qw);
        qx = qx / nrm; qy = qy / nrm; qz = qz / nrm; qw = qw / nrm;
        float dx = px - tx, dy = py - ty, dz = pz - tz;
        float rx, ry, rz;
        rot_inv(qx, qy, qz, qw, dx, dy, dz, rx, ry, rz);
        const float* ww = widths + (size_t)bn * 3;
        float gx = rx / ww[0] - 0.5f;
        float gy = ry / ww[1] - 0.5f;
        float gz = rz / ww[2] - 0.5f;
        int SX = sdf_shapes[m * 3 + 0];
        int SY = sdf_shapes[m * 3 + 1];
        int SZ = sdf_shapes[m * 3 + 2];
        float mx = (float)(SX - 1), my = (float)(SY - 1), mz = (float)(SZ - 1);
        bool inside = (gx >= 0.0f) && (gx <= mx) &&
                      (gy >= 0.0f) && (gy <= my) &&
                      (gz >= 0.0f) && (gz <= mz);
        float fx = fminf(fmaxf(gx, 0.0f), mx);
        float fy = fminf(fmaxf(gy, 0.0f), my);
        float fz = fminf(fmaxf(gz, 0.0f), mz);
        int i0x = (int)floorf(fx), i0y = (int)floorf(fy), i0z = (int)floorf(fz);
        float frx = fx - (float)i0x, fry = fy - (float)i0y, frz = fz - (float)i0z;
        int i1x = min(i0x + 1, SX - 1);
        int i1y = min(i0y + 1, SY - 1);
        int i1z = min(i0z + 1, SZ - 1);
        const float* sd = sdfs + (size_t)m * sdf_stride;
        int b00 = (i0x * SY + i0y) * SZ;
        int b01 = (i0x * SY + i1y) * SZ;
        int b10 = (i1x * SY + i0y) * SZ;
        int b11 = (i1x * SY + i1y) * SZ;
        float v000 = sd[b00 + i0z], v001 = sd[b00 + i1z];
        float v010 = sd[b01 + i0z], v011 = sd[b01 + i1z];
        float v100 = sd[b10 + i0z], v101 = sd[b10 + i1z];
        float v110 = sd[b11 + i0z], v111 = sd[b11 + i1z];
        float wx0 = 1.0f - frx, wx1 = frx;
        float wy0 = 1.0f - fry, wy1 = fry;
        float wz0 = 1.0f - frz, wz1 = frz;
        float acc = wx0 * wy0 * wz0 * v000 + wx0 * wy0 * wz1 * v001
                  + wx0 * wy1 * wz0 * v010 + wx0 * wy1 * wz1 * v011
                  + wx1 * wy0 * wz0 * v100 + wx1 * wy0 * wz1 * v101
                  + wx1 * wy1 * wz0 * v110 + wx1 * wy1 * wz1 * v111;
        float val = inside ? acc : BIGF;
        best = fminf(best, val);
    }
    out[idx] = best;
}

extern "C" void kernel_launch(void* const* d_in, const int* in_sizes, int n_in,
                              void* d_out, int out_size, void* d_ws, size_t ws_size,
                              hipStream_t stream) {
    const float* sdfs    = (const float*)d_in[0];
    const int*   shapes  = (const int*)d_in[1];
    const int*   indices = (const int*)d_in[2];
    const float* poses   = (const float*)d_in[3];
    const float* widths  = (const float*)d_in[4];
    float*       out     = (float*)d_out;

    int M = in_sizes[1] / 3;           // sdf_shapes is (M,3)
    int sdf_stride = in_sizes[0] / M;  // elements per SDF volume
    int B = out_size / PTS_PER_B;
    int N = in_sizes[2] / B;           // indices is (B,N)
    int BN = B * N;

    size_t ws_needed = (size_t)BN * RECSZ * sizeof(float);

    if (ws_size >= ws_needed && N <= 32 && (PTS_PER_B % 256) == 0) {
        float* rec = (float*)d_ws;
        prep_v5<<<(BN + 63) / 64, 64, 0, stream>>>(
            shapes, indices, poses, widths, rec, BN, sdf_stride);
        dim3 grid(BLOCKS_PER_B, B);
        sdf_grid_v5<<<grid, 256, 0, stream>>>(sdfs, rec, out, N);
    } else {
        int total = out_size;
        int blocks = (total + 255) / 256;
        sdf_grid_kernel<<<blocks, 256, 0, stream>>>(
            sdfs, shapes, indices, poses, widths, out, total, N, sdf_stride);
    }
}

// Round 7
// 29.623 us; speedup vs baseline: 1.1745x; 1.1745x over previous
//
#include <hip/hip_runtime.h>

#define GXD 96
#define GYD 96
#define GZD 96
#define PTS_PER_B (GXD * GYD * GZD)
#define BLOCKS_PER_B (PTS_PER_B / 256)   // 3456
#define RECSZ 56
#define BIGF 1e10f
#define GLOWER -1.2f
#define GSTEP 0.025f

// ---------- exact rotate: identical op order to validated rounds ----------
__device__ __forceinline__ void rot_inv(float qx, float qy, float qz, float qw,
                                        float dx, float dy, float dz,
                                        float& rx, float& ry, float& rz)
{
    float ux = -qx, uy = -qy, uz = -qz;
    float uvx = uy * dz - uz * dy;
    float uvy = uz * dx - ux * dz;
    float uvz = ux * dy - uy * dx;
    float t2x = uvx + qw * dx;
    float t2y = uvy + qw * dy;
    float t2z = uvz + qw * dz;
    rx = dx + 2.0f * (uy * t2z - uz * t2y);
    ry = dy + 2.0f * (uz * t2x - ux * t2z);
    rz = dz + 2.0f * (ux * t2y - uy * t2x);
}

__device__ __forceinline__ float next_up(float a) { return __uint_as_float(__float_as_uint(a) + 1u); }
__device__ __forceinline__ float next_dn(float a) { return __uint_as_float(__float_as_uint(a) - 1u); }

// smallest positive float a with fl(a/w) >= t   (w>0, t>0; start within ~3 ulp)
__device__ float exact_lo(float w, float t)
{
    float a = t * w;
    while (a / w < t)            a = next_up(a);
    while (next_dn(a) / w >= t)  a = next_dn(a);
    return a;
}

// largest positive float a with fl(a/w) <= L
__device__ float exact_hi(float w, float L)
{
    float a = L * w;
    while (a / w > L)            a = next_dn(a);
    while (next_up(a) / w <= L)  a = next_up(a);
    return a;
}

// record layout (floats unless noted):
//  0-2  t      3-6  q(normalized)    7-9  invw=fl(1/w)
// 10-12 (S-1)f 13-15 A (exact lo)   16-18 B (exact hi)
// 19 (int) m*sdf_stride  20-22 (int) SX,SY,SZ  23 pad
// 24-26 world AABB lo    27-29 world AABB hi   30-31 pad
// 32-40 M = R^T row-major (world->local matrix rotate)
// 41-43 wideLo = A-EPS   44-46 wideHi = B+EPS
// 47 pad
// 48-50 narrowLo = A+EPS 51-53 narrowHi = B-EPS  54-55 pad
__global__ void prep_v6(const int* __restrict__ shapes,
                        const int* __restrict__ indices,
                        const float* __restrict__ poses,
                        const float* __restrict__ widths,
                        float* __restrict__ rec,
                        int BN, int sdf_stride)
{
    int bn = blockIdx.x * blockDim.x + threadIdx.x;
    if (bn >= BN) return;
    int m = indices[bn];
    const float* pp = poses + (size_t)bn * 7;
    float tx = pp[0], ty = pp[1], tz = pp[2];
    float qx = pp[3], qy = pp[4], qz = pp[5], qw = pp[6];
    // identical op order to validated rounds -> bit-identical q
    float nrm = sqrtf(qx * qx + qy * qy + qz * qz + qw * qw);
    qx = qx / nrm; qy = qy / nrm; qz = qz / nrm; qw = qw / nrm;

    float wx = widths[bn * 3 + 0], wy = widths[bn * 3 + 1], wz = widths[bn * 3 + 2];
    int SX = shapes[m * 3 + 0], SY = shapes[m * 3 + 1], SZ = shapes[m * 3 + 2];
    float mx = (float)(SX - 1), my = (float)(SY - 1), mz = (float)(SZ - 1);

    // inside_x <=> fl(rx/w) in [0.5, mx+0.5] <=> rx in [A,B] (division monotone,
    // u-0.5 Sterbenz-exact on the decision range) — validated rounds 2-5
    float Ax = exact_lo(wx, 0.5f), Ay = exact_lo(wy, 0.5f), Az = exact_lo(wz, 0.5f);
    float Bx = exact_hi(wx, mx + 0.5f), By = exact_hi(wy, my + 0.5f), Bz = exact_hi(wz, mz + 0.5f);

    // rotation matrix R (local->world) from q; M = R^T (world->local)
    float xx = qx * qx, yy = qy * qy, zz = qz * qz;
    float xy = qx * qy, xz = qx * qz, yz = qy * qz;
    float wqx = qw * qx, wqy = qw * qy, wqz = qw * qz;
    float R00 = 1.0f - 2.0f * (yy + zz), R01 = 2.0f * (xy - wqz), R02 = 2.0f * (xz + wqy);
    float R10 = 2.0f * (xy + wqz), R11 = 1.0f - 2.0f * (xx + zz), R12 = 2.0f * (yz - wqx);
    float R20 = 2.0f * (xz - wqy), R21 = 2.0f * (yz + wqx), R22 = 1.0f - 2.0f * (xx + yy);

    // conservative world AABB of the exact local box [A,B] (validated round 4)
    float cx = 0.5f * (Ax + Bx), cy = 0.5f * (Ay + By), cz = 0.5f * (Az + Bz);
    float hx = 0.5f * (Bx - Ax), hy = 0.5f * (By - Ay), hz = 0.5f * (Bz - Az);
    const float MARG = 2e-3f;  // >> rotation/rounding error (~1e-6)
    float wcx = tx + R00 * cx + R01 * cy + R02 * cz;
    float wcy = ty + R10 * cx + R11 * cy + R12 * cz;
    float wcz = tz + R20 * cx + R21 * cy + R22 * cz;
    float ex = fabsf(R00) * hx + fabsf(R01) * hy + fabsf(R02) * hz + MARG;
    float ey = fabsf(R10) * hx + fabsf(R11) * hy + fabsf(R12) * hz + MARG;
    float ez = fabsf(R20) * hx + fabsf(R21) * hy + fabsf(R22) * hz + MARG;

    // two-sided margin: |matrix-path l - chain-path r| <= ~5e-6; EPS = 40x that
    const float EPS = 2e-4f;

    float* r = rec + (size_t)bn * RECSZ;
    r[0] = tx;  r[1] = ty;  r[2] = tz;
    r[3] = qx;  r[4] = qy;  r[5] = qz;  r[6] = qw;
    r[7] = 1.0f / wx; r[8] = 1.0f / wy; r[9] = 1.0f / wz;
    r[10] = mx; r[11] = my; r[12] = mz;
    r[13] = Ax; r[14] = Ay; r[15] = Az;
    r[16] = Bx; r[17] = By; r[18] = Bz;
    int* ri = (int*)r;
    ri[19] = m * sdf_stride;
    ri[20] = SX; ri[21] = SY; ri[22] = SZ;
    r[23] = 0.0f;
    r[24] = wcx - ex; r[25] = wcy - ey; r[26] = wcz - ez;
    r[27] = wcx + ex; r[28] = wcy + ey; r[29] = wcz + ez;
    r[30] = 0.0f; r[31] = 0.0f;
    r[32] = R00; r[33] = R10; r[34] = R20;   // M = R^T rows
    r[35] = R01; r[36] = R11; r[37] = R21;
    r[38] = R02; r[39] = R12; r[40] = R22;
    r[41] = Ax - EPS; r[42] = Ay - EPS; r[43] = Az - EPS;
    r[44] = Bx + EPS; r[45] = By + EPS; r[46] = Bz + EPS;
    r[47] = 0.0f;
    r[48] = Ax + EPS; r[49] = Ay + EPS; r[50] = Az + EPS;
    r[51] = Bx - EPS; r[52] = By - EPS; r[53] = Bz - EPS;
    r[54] = 0.0f; r[55] = 0.0f;
}

// per-(batch, 256-thread block) conservative SDF overlap mask (validated round 4)
__global__ void prep_mask(const float* __restrict__ rec,
                          unsigned int* __restrict__ mask,
                          int N, int totalBlocks)
{
    int gid = blockIdx.x * blockDim.x + threadIdx.x;
    if (gid >= totalBlocks) return;
    int b  = gid / BLOCKS_PER_B;
    int bx = gid % BLOCKS_PER_B;

    int pid0 = bx * 256;               // block spans pids [pid0, pid0+255]
    int col0 = pid0 / GZD;
    int col2 = (pid0 + 255) / GZD;
    int x  = col0 / GYD;               // single x-slab (9216 pts = 36 blocks)
    int y0 = col0 % GYD;
    int y2 = col2 % GYD;

    float px  = GLOWER + ((float)x + 0.5f) * GSTEP;
    float pyl = GLOWER + ((float)y0 + 0.5f) * GSTEP;
    float pyh = GLOWER + ((float)y2 + 0.5f) * GSTEP;
    float pzl = GLOWER + 0.5f * GSTEP;
    float pzh = GLOWER + ((float)(GZD - 1) + 0.5f) * GSTEP;

    unsigned int msk = 0u;
    for (int n = 0; n < N; ++n) {
        const float* r = rec + (size_t)(b * N + n) * RECSZ;
        bool ok = (px  >= r[24]) & (px  <= r[27]) &
                  (pyh >= r[25]) & (pyl <= r[28]) &
                  (pzh >= r[26]) & (pzl <= r[29]);
        msk |= (ok ? 1u : 0u) << n;
    }
    mask[gid] = msk;
}

struct __attribute__((aligned(4))) F2 { float lo, hi; };

__device__ __forceinline__ float trilerp2(const float* __restrict__ sd,
                                          float rx, float ry, float rz,
                                          float invwx, float invwy, float invwz,
                                          float mx, float my, float mz,
                                          int SX, int SY, int SZ)
{
    // value-only path: decision already made; ~ulp-level value error irrelevant
    float gx = rx * invwx - 0.5f;
    float gy = ry * invwy - 0.5f;
    float gz = rz * invwz - 0.5f;
    float fx = fminf(fmaxf(gx, 0.0f), mx);
    float fy = fminf(fmaxf(gy, 0.0f), my);
    float fz = fminf(fmaxf(gz, 0.0f), mz);
    int i0x = (int)fx, i0y = (int)fy, i0z = (int)fz;  // f>=0 -> trunc==floor
    float frx = fx - (float)i0x;
    float fry = fy - (float)i0y;
    float frz = fz - (float)i0z;
    int i1x = min(i0x + 1, SX - 1);
    int i1y = min(i0y + 1, SY - 1);

    // paired-z gather: (v_z0, v_z0+1) contiguous; exact edge clamp via select.
    // zb = min(i0z, SZ-2): if i0z<=SZ-2 -> v000=lo, v001=hi(=i0z+1);
    // if i0z==SZ-1 -> zb=SZ-2, v000=hi(=i0z), v001=hi (both clamp to SZ-1). Exact.
    int zb = min(i0z, max(SZ - 2, 0));
    bool at0 = (i0z == zb);

    int b00 = (i0x * SY + i0y) * SZ + zb;
    int b01 = (i0x * SY + i1y) * SZ + zb;
    int b10 = (i1x * SY + i0y) * SZ + zb;
    int b11 = (i1x * SY + i1y) * SZ + zb;

    F2 p00 = *(const F2*)(sd + b00);
    F2 p01 = *(const F2*)(sd + b01);
    F2 p10 = *(const F2*)(sd + b10);
    F2 p11 = *(const F2*)(sd + b11);

    float v000 = at0 ? p00.lo : p00.hi, v001 = p00.hi;
    float v010 = at0 ? p01.lo : p01.hi, v011 = p01.hi;
    float v100 = at0 ? p10.lo : p10.hi, v101 = p10.hi;
    float v110 = at0 ? p11.lo : p11.hi, v111 = p11.hi;

    float c00 = v000 + frz * (v001 - v000);
    float c01 = v010 + frz * (v011 - v010);
    float c10 = v100 + frz * (v101 - v100);
    float c11 = v110 + frz * (v111 - v110);
    float c0 = c00 + fry * (c01 - c00);
    float c1 = c10 + fry * (c11 - c10);
    return c0 + frx * (c1 - c0);
}

__global__ __launch_bounds__(256) void sdf_grid_v6(
    const float* __restrict__ sdfs,
    const float* __restrict__ rec,
    const unsigned int* __restrict__ mask,
    float* __restrict__ out,
    int N)
{
    int pid = blockIdx.x * blockDim.x + threadIdx.x;  // z innermost
    int b = blockIdx.y;

    int z = pid % GZD;
    int y = (pid / GZD) % GYD;
    int x = pid / (GZD * GYD);

    float px = GLOWER + ((float)x + 0.5f) * GSTEP;
    float py = GLOWER + ((float)y + 0.5f) * GSTEP;
    float pz = GLOWER + ((float)z + 0.5f) * GSTEP;

    unsigned int msk = mask[b * BLOCKS_PER_B + blockIdx.x];  // uniform -> s_load

    float best = BIGF;

    for (int n = 0; n < N; ++n) {
        if (!((msk >> n) & 1u)) continue;  // whole block certainly outside SDF n

        const float* r = rec + (size_t)(b * N + n) * RECSZ;  // wave-uniform -> s_load
        float dx = px - r[0], dy = py - r[1], dz = pz - r[2];

        // cheap matrix rotate (replaces chain for all non-sliver points)
        float lx = r[32] * dx + r[33] * dy + r[34] * dz;
        float ly = r[35] * dx + r[36] * dy + r[37] * dz;
        float lz = r[38] * dx + r[39] * dy + r[40] * dz;

        // certainly-outside: any axis beyond wide bounds
        bool wide = (lx >= r[41]) & (lx <= r[44]) &
                    (ly >= r[42]) & (ly <= r[45]) &
                    (lz >= r[43]) & (lz <= r[46]);
        if (!wide) continue;

        // certainly-inside: all axes within narrow bounds
        bool narrow = (lx >= r[48]) & (lx <= r[51]) &
                      (ly >= r[49]) & (ly <= r[52]) &
                      (lz >= r[50]) & (lz <= r[53]);

        float rx = lx, ry = ly, rz = lz;
        bool inside = true;
        if (!narrow) {
            // sliver: exact recompute, identical chain -> bit-identical decision
            rot_inv(r[3], r[4], r[5], r[6], dx, dy, dz, rx, ry, rz);
            inside = (rx >= r[13]) & (rx <= r[16]) &
                     (ry >= r[14]) & (ry <= r[17]) &
                     (rz >= r[15]) & (rz <= r[18]);
        }
        if (inside) {
            const int* ri = (const int*)r;
            float v = trilerp2(sdfs + ri[19], rx, ry, rz,
                               r[7], r[8], r[9], r[10], r[11], r[12],
                               ri[20], ri[21], ri[22]);
            best = fminf(best, v);
        }
    }

    out[(size_t)b * PTS_PER_B + pid] = best;
}

// ---------------- fallback: round-0 validated monolithic kernel ----------------
__global__ __launch_bounds__(256) void sdf_grid_kernel(
    const float* __restrict__ sdfs,
    const int*   __restrict__ sdf_shapes,
    const int*   __restrict__ indices,
    const float* __restrict__ poses,
    const float* __restrict__ widths,
    float*       __restrict__ out,
    int total, int N, int sdf_stride)
{
    int idx = blockIdx.x * blockDim.x + threadIdx.x;
    if (idx >= total) return;
    int z = idx % GZD;
    int y = (idx / GZD) % GYD;
    int x = (idx / (GZD * GYD)) % GXD;
    int b = idx / (GZD * GYD * GXD);
    float px = GLOWER + ((float)x + 0.5f) * GSTEP;
    float py = GLOWER + ((float)y + 0.5f) * GSTEP;
    float pz = GLOWER + ((float)z + 0.5f) * GSTEP;
    float best = BIGF;
    for (int n = 0; n < N; ++n) {
        int bn = b * N + n;
        int m  = indices[bn];
        const float* pp = poses + (size_t)bn * 7;
        float tx = pp[0], ty = pp[1], tz = pp[2];
        float qx = pp[3], qy = pp[4], qz = pp[5], qw = pp[6];
        float nrm = sqrtf(qx * qx + qy * qy + qz * qz + qw * qw);
        qx = qx / nrm; qy = qy / nrm; qz = qz / nrm; qw = qw / nrm;
        float dx = px - tx, dy = py - ty, dz = pz - tz;
        float rx, ry, rz;
        rot_inv(qx, qy, qz, qw, dx, dy, dz, rx, ry, rz);
        const float* ww = widths + (size_t)bn * 3;
        float gx = rx / ww[0] - 0.5f;
        float gy = ry / ww[1] - 0.5f;
        float gz = rz / ww[2] - 0.5f;
        int SX = sdf_shapes[m * 3 + 0];
        int SY = sdf_shapes[m * 3 + 1];
        int SZ = sdf_shapes[m * 3 + 2];
        float mx = (float)(SX - 1), my = (float)(SY - 1), mz = (float)(SZ - 1);
        bool inside = (gx >= 0.0f) && (gx <= mx) &&
                      (gy >= 0.0f) && (gy <= my) &&
                      (gz >= 0.0f) && (gz <= mz);
        float fx = fminf(fmaxf(gx, 0.0f), mx);
        float fy = fminf(fmaxf(gy, 0.0f), my);
        float fz = fminf(fmaxf(gz, 0.0f), mz);
        int i0x = (int)floorf(fx), i0y = (int)floorf(fy), i0z = (int)floorf(fz);
        float frx = fx - (float)i0x, fry = fy - (float)i0y, frz = fz - (float)i0z;
        int i1x = min(i0x + 1, SX - 1);
        int i1y = min(i0y + 1, SY - 1);
        int i1z = min(i0z + 1, SZ - 1);
        const float* sd = sdfs + (size_t)m * sdf_stride;
        int b00 = (i0x * SY + i0y) * SZ;
        int b01 = (i0x * SY + i1y) * SZ;
        int b10 = (i1x * SY + i0y) * SZ;
        int b11 = (i1x * SY + i1y) * SZ;
        float v000 = sd[b00 + i0z], v001 = sd[b00 + i1z];
        float v010 = sd[b01 + i0z], v011 = sd[b01 + i1z];
        float v100 = sd[b10 + i0z], v101 = sd[b10 + i1z];
        float v110 = sd[b11 + i0z], v111 = sd[b11 + i1z];
        float wx0 = 1.0f - frx, wx1 = frx;
        float wy0 = 1.0f - fry, wy1 = fry;
        float wz0 = 1.0f - frz, wz1 = frz;
        float acc = wx0 * wy0 * wz0 * v000 + wx0 * wy0 * wz1 * v001
                  + wx0 * wy1 * wz0 * v010 + wx0 * wy1 * wz1 * v011
                  + wx1 * wy0 * wz0 * v100 + wx1 * wy0 * wz1 * v101
                  + wx1 * wy1 * wz0 * v110 + wx1 * wy1 * wz1 * v111;
        float val = inside ? acc : BIGF;
        best = fminf(best, val);
    }
    out[idx] = best;
}

extern "C" void kernel_launch(void* const* d_in, const int* in_sizes, int n_in,
                              void* d_out, int out_size, void* d_ws, size_t ws_size,
                              hipStream_t stream) {
    const float* sdfs    = (const float*)d_in[0];
    const int*   shapes  = (const int*)d_in[1];
    const int*   indices = (const int*)d_in[2];
    const float* poses   = (const float*)d_in[3];
    const float* widths  = (const float*)d_in[4];
    float*       out     = (float*)d_out;

    int M = in_sizes[1] / 3;           // sdf_shapes is (M,3)
    int sdf_stride = in_sizes[0] / M;  // elements per SDF volume
    int B = out_size / PTS_PER_B;
    int N = in_sizes[2] / B;           // indices is (B,N)
    int BN = B * N;
    int totalBlocks = B * BLOCKS_PER_B;

    size_t rec_bytes  = (size_t)BN * RECSZ * sizeof(float);
    size_t rec_pad    = (rec_bytes + 255) & ~(size_t)255;
    size_t mask_bytes = (size_t)totalBlocks * sizeof(unsigned int);
    size_t ws_needed  = rec_pad + mask_bytes;

    if (ws_size >= ws_needed && N <= 32 && (PTS_PER_B % 256) == 0) {
        float* rec = (float*)d_ws;
        unsigned int* mask = (unsigned int*)((char*)d_ws + rec_pad);

        prep_v6<<<(BN + 63) / 64, 64, 0, stream>>>(
            shapes, indices, poses, widths, rec, BN, sdf_stride);
        prep_mask<<<(totalBlocks + 255) / 256, 256, 0, stream>>>(
            rec, mask, N, totalBlocks);
        dim3 grid(BLOCKS_PER_B, B);
        sdf_grid_v6<<<grid, 256, 0, stream>>>(sdfs, rec, mask, out, N);
    } else {
        int total = out_size;
        int blocks = (total + 255) / 256;
        sdf_grid_kernel<<<blocks, 256, 0, stream>>>(
            sdfs, shapes, indices, poses, widths, out, total, N, sdf_stride);
    }
}

// Round 8
// 27.301 us; speedup vs baseline: 1.2744x; 1.0850x over previous
//
#include <hip/hip_runtime.h>

#define GXD 96
#define GYD 96
#define GZD 96
#define PTS_PER_B (GXD * GYD * GZD)
#define BLOCKS_PER_B (PTS_PER_B / 256)   // 3456
#define RECSZ 56
#define BIGF 1e10f
#define GLOWER -1.2f
#define GSTEP 0.025f
#define EPS_G 1e-2f   // two-sided cull margin in g-units; |sg - g_ref| <= ~3e-4

// ---------- exact rotate: identical op order to validated rounds ----------
__device__ __forceinline__ void rot_inv(float qx, float qy, float qz, float qw,
                                        float dx, float dy, float dz,
                                        float& rx, float& ry, float& rz)
{
    float ux = -qx, uy = -qy, uz = -qz;
    float uvx = uy * dz - uz * dy;
    float uvy = uz * dx - ux * dz;
    float uvz = ux * dy - uy * dx;
    float t2x = uvx + qw * dx;
    float t2y = uvy + qw * dy;
    float t2z = uvz + qw * dz;
    rx = dx + 2.0f * (uy * t2z - uz * t2y);
    ry = dy + 2.0f * (uz * t2x - ux * t2z);
    rz = dz + 2.0f * (ux * t2y - uy * t2x);
}

__device__ __forceinline__ float next_up(float a) { return __uint_as_float(__float_as_uint(a) + 1u); }
__device__ __forceinline__ float next_dn(float a) { return __uint_as_float(__float_as_uint(a) - 1u); }

// smallest positive float a with fl(a/w) >= t   (w>0, t>0; start within ~3 ulp)
__device__ float exact_lo(float w, float t)
{
    float a = t * w;
    while (a / w < t)            a = next_up(a);
    while (next_dn(a) / w >= t)  a = next_dn(a);
    return a;
}

// largest positive float a with fl(a/w) <= L
__device__ float exact_hi(float w, float L)
{
    float a = L * w;
    while (a / w > L)            a = next_dn(a);
    while (next_up(a) / w <= L)  a = next_up(a);
    return a;
}

// record layout (floats unless noted):
//  0-2  t      3-6  q(normalized)    7-9  invw=fl(1/w)
// 10-12 mx,my,mz=(S-1)f
// 13-15 A (exact lo)   16-18 B (exact hi)
// 19 (int) m*sdf_stride  20-22 (int) SX,SY,SZ  23 pad
// 24-26 world AABB lo    27-29 world AABB hi   30-31 pad
// 32-40 Mg = diag(invw)*R^T rows  41-43 Cg = -Mg*t - 0.5   (sg = Mg*p + Cg ~ g)
// 44-46 wideHi = mx + EPS_G   47 pad
// 48-50 narrowHi = mx - EPS_G 51-55 pad
__global__ void prep_v7(const int* __restrict__ shapes,
                        const int* __restrict__ indices,
                        const float* __restrict__ poses,
                        const float* __restrict__ widths,
                        float* __restrict__ rec,
                        int BN, int sdf_stride)
{
    int bn = blockIdx.x * blockDim.x + threadIdx.x;
    if (bn >= BN) return;
    int m = indices[bn];
    const float* pp = poses + (size_t)bn * 7;
    float tx = pp[0], ty = pp[1], tz = pp[2];
    float qx = pp[3], qy = pp[4], qz = pp[5], qw = pp[6];
    // identical op order to validated rounds -> bit-identical q
    float nrm = sqrtf(qx * qx + qy * qy + qz * qz + qw * qw);
    qx = qx / nrm; qy = qy / nrm; qz = qz / nrm; qw = qw / nrm;

    float wx = widths[bn * 3 + 0], wy = widths[bn * 3 + 1], wz = widths[bn * 3 + 2];
    int SX = shapes[m * 3 + 0], SY = shapes[m * 3 + 1], SZ = shapes[m * 3 + 2];
    float mx = (float)(SX - 1), my = (float)(SY - 1), mz = (float)(SZ - 1);

    // inside_x <=> fl(rx/w) in [0.5, mx+0.5] <=> rx in [A,B] (division monotone,
    // u-0.5 Sterbenz-exact on the decision range) — validated rounds 2-6
    float Ax = exact_lo(wx, 0.5f), Ay = exact_lo(wy, 0.5f), Az = exact_lo(wz, 0.5f);
    float Bx = exact_hi(wx, mx + 0.5f), By = exact_hi(wy, my + 0.5f), Bz = exact_hi(wz, mz + 0.5f);

    // rotation matrix R (local->world) from q
    float xx = qx * qx, yy = qy * qy, zz = qz * qz;
    float xy = qx * qy, xz = qx * qz, yz = qy * qz;
    float wqx = qw * qx, wqy = qw * qy, wqz = qw * qz;
    float R00 = 1.0f - 2.0f * (yy + zz), R01 = 2.0f * (xy - wqz), R02 = 2.0f * (xz + wqy);
    float R10 = 2.0f * (xy + wqz), R11 = 1.0f - 2.0f * (xx + zz), R12 = 2.0f * (yz - wqx);
    float R20 = 2.0f * (xz - wqy), R21 = 2.0f * (yz + wqx), R22 = 1.0f - 2.0f * (xx + yy);

    // conservative world AABB of the exact local box [A,B] (validated round 4)
    float cx = 0.5f * (Ax + Bx), cy = 0.5f * (Ay + By), cz = 0.5f * (Az + Bz);
    float hx = 0.5f * (Bx - Ax), hy = 0.5f * (By - Ay), hz = 0.5f * (Bz - Az);
    const float MARG = 2e-3f;  // >> rotation/rounding error (~1e-6)
    float wcx = tx + R00 * cx + R01 * cy + R02 * cz;
    float wcy = ty + R10 * cx + R11 * cy + R12 * cz;
    float wcz = tz + R20 * cx + R21 * cy + R22 * cz;
    float ex = fabsf(R00) * hx + fabsf(R01) * hy + fabsf(R02) * hz + MARG;
    float ey = fabsf(R10) * hx + fabsf(R11) * hy + fabsf(R12) * hz + MARG;
    float ez = fabsf(R20) * hx + fabsf(R21) * hy + fabsf(R22) * hz + MARG;

    float iwx = 1.0f / wx, iwy = 1.0f / wy, iwz = 1.0f / wz;
    // g-space affine map: sg = Mg*p + Cg, Mg rows = invw_axis * (R^T row)
    float Mg0x = iwx * R00, Mg1x = iwx * R10, Mg2x = iwx * R20;
    float Mg0y = iwy * R01, Mg1y = iwy * R11, Mg2y = iwy * R21;
    float Mg0z = iwz * R02, Mg1z = iwz * R12, Mg2z = iwz * R22;
    float Cgx = -0.5f - (Mg0x * tx + Mg1x * ty + Mg2x * tz);
    float Cgy = -0.5f - (Mg0y * tx + Mg1y * ty + Mg2y * tz);
    float Cgz = -0.5f - (Mg0z * tx + Mg1z * ty + Mg2z * tz);

    float* r = rec + (size_t)bn * RECSZ;
    r[0] = tx;  r[1] = ty;  r[2] = tz;
    r[3] = qx;  r[4] = qy;  r[5] = qz;  r[6] = qw;
    r[7] = iwx; r[8] = iwy; r[9] = iwz;
    r[10] = mx; r[11] = my; r[12] = mz;
    r[13] = Ax; r[14] = Ay; r[15] = Az;
    r[16] = Bx; r[17] = By; r[18] = Bz;
    int* ri = (int*)r;
    ri[19] = m * sdf_stride;
    ri[20] = SX; ri[21] = SY; ri[22] = SZ;
    r[23] = 0.0f;
    r[24] = wcx - ex; r[25] = wcy - ey; r[26] = wcz - ez;
    r[27] = wcx + ex; r[28] = wcy + ey; r[29] = wcz + ez;
    r[30] = 0.0f; r[31] = 0.0f;
    r[32] = Mg0x; r[33] = Mg1x; r[34] = Mg2x;
    r[35] = Mg0y; r[36] = Mg1y; r[37] = Mg2y;
    r[38] = Mg0z; r[39] = Mg1z; r[40] = Mg2z;
    r[41] = Cgx; r[42] = Cgy; r[43] = Cgz;
    r[44] = mx + EPS_G; r[45] = my + EPS_G; r[46] = mz + EPS_G;
    r[47] = 0.0f;
    r[48] = mx - EPS_G; r[49] = my - EPS_G; r[50] = mz - EPS_G;
    r[51] = 0.0f; r[52] = 0.0f; r[53] = 0.0f; r[54] = 0.0f; r[55] = 0.0f;
}

struct __attribute__((aligned(4))) F2 { float lo, hi; };

// trilerp taking g directly (validated paired-z gather from round 6)
__device__ __forceinline__ float trilerp_g(const float* __restrict__ sd,
                                           float gx, float gy, float gz,
                                           float mx, float my, float mz,
                                           int SX, int SY, int SZ)
{
    float fx = fminf(fmaxf(gx, 0.0f), mx);
    float fy = fminf(fmaxf(gy, 0.0f), my);
    float fz = fminf(fmaxf(gz, 0.0f), mz);
    int i0x = (int)fx, i0y = (int)fy, i0z = (int)fz;  // f>=0 -> trunc==floor
    float frx = fx - (float)i0x;
    float fry = fy - (float)i0y;
    float frz = fz - (float)i0z;
    int i1x = min(i0x + 1, SX - 1);
    int i1y = min(i0y + 1, SY - 1);

    // paired-z gather with exact edge clamp (validated round 6)
    int zb = min(i0z, max(SZ - 2, 0));
    bool at0 = (i0z == zb);

    int b00 = (i0x * SY + i0y) * SZ + zb;
    int b01 = (i0x * SY + i1y) * SZ + zb;
    int b10 = (i1x * SY + i0y) * SZ + zb;
    int b11 = (i1x * SY + i1y) * SZ + zb;

    F2 p00 = *(const F2*)(sd + b00);
    F2 p01 = *(const F2*)(sd + b01);
    F2 p10 = *(const F2*)(sd + b10);
    F2 p11 = *(const F2*)(sd + b11);

    float v000 = at0 ? p00.lo : p00.hi, v001 = p00.hi;
    float v010 = at0 ? p01.lo : p01.hi, v011 = p01.hi;
    float v100 = at0 ? p10.lo : p10.hi, v101 = p10.hi;
    float v110 = at0 ? p11.lo : p11.hi, v111 = p11.hi;

    float c00 = v000 + frz * (v001 - v000);
    float c01 = v010 + frz * (v011 - v010);
    float c10 = v100 + frz * (v101 - v100);
    float c11 = v110 + frz * (v111 - v110);
    float c0 = c00 + fry * (c01 - c00);
    float c1 = c10 + fry * (c11 - c10);
    return c0 + frx * (c1 - c0);
}

__global__ __launch_bounds__(256) void sdf_grid_v7(
    const float* __restrict__ sdfs,
    const float* __restrict__ rec,
    float* __restrict__ out,
    int N)
{
    int pid = blockIdx.x * blockDim.x + threadIdx.x;  // z innermost
    int b = blockIdx.y;

    int z = pid % GZD;
    int y = (pid / GZD) % GYD;
    int x = pid / (GZD * GYD);

    float px = GLOWER + ((float)x + 0.5f) * GSTEP;
    float py = GLOWER + ((float)y + 0.5f) * GSTEP;
    float pz = GLOWER + ((float)z + 0.5f) * GSTEP;

    size_t out_idx = (size_t)b * PTS_PER_B + pid;

    // ---- per-wave ballot block mask (same AABB test as validated prep_mask) ----
    // block spans one x-slab (9216 pts = 36 blocks), cols [col0, col0+2]
    int pid0 = blockIdx.x * 256;
    int col0 = pid0 / GZD;
    int col2 = (pid0 + 255) / GZD;
    float bpx  = GLOWER + ((float)(col0 / GYD) + 0.5f) * GSTEP;
    float bpyl = GLOWER + ((float)(col0 % GYD) + 0.5f) * GSTEP;
    float bpyh = GLOWER + ((float)(col2 % GYD) + 0.5f) * GSTEP;
    float bpzl = GLOWER + 0.5f * GSTEP;
    float bpzh = GLOWER + ((float)(GZD - 1) + 0.5f) * GSTEP;

    int lane = threadIdx.x & 63;
    bool lok = false;
    if (lane < N) {
        const float* r = rec + (size_t)(b * N + lane) * RECSZ;
        lok = (bpx  >= r[24]) & (bpx  <= r[27]) &
              (bpyh >= r[25]) & (bpyl <= r[28]) &
              (bpzh >= r[26]) & (bpzl <= r[29]);
    }
    unsigned int msk = (unsigned int)__ballot(lok);

    if (msk == 0u) { out[out_idx] = BIGF; return; }

    float best = BIGF;

    for (int n = 0; n < N; ++n) {
        if (!((msk >> n) & 1u)) continue;  // whole block certainly outside SDF n

        const float* r = rec + (size_t)(b * N + n) * RECSZ;  // wave-uniform -> s_load

        // g-space affine rotate: sg ~ reference g, |err| <= ~3e-4 << EPS_G
        float sgx = fmaf(r[32], px, fmaf(r[33], py, fmaf(r[34], pz, r[41])));
        float sgy = fmaf(r[35], px, fmaf(r[36], py, fmaf(r[37], pz, r[42])));
        float sgz = fmaf(r[38], px, fmaf(r[39], py, fmaf(r[40], pz, r[43])));

        // certainly-outside: any axis beyond wide bounds
        bool wide = (sgx >= -EPS_G) & (sgx <= r[44]) &
                    (sgy >= -EPS_G) & (sgy <= r[45]) &
                    (sgz >= -EPS_G) & (sgz <= r[46]);
        if (!wide) continue;

        // certainly-inside: all axes within narrow bounds
        bool narrow = (sgx >= EPS_G) & (sgx <= r[48]) &
                      (sgy >= EPS_G) & (sgy <= r[49]) &
                      (sgz >= EPS_G) & (sgz <= r[50]);

        float gx = sgx, gy = sgy, gz = sgz;
        bool inside = true;
        if (!narrow) {
            // sliver: exact recompute, identical chain -> bit-identical decision
            float dx = px - r[0], dy = py - r[1], dz = pz - r[2];
            float rx, ry, rz;
            rot_inv(r[3], r[4], r[5], r[6], dx, dy, dz, rx, ry, rz);
            inside = (rx >= r[13]) & (rx <= r[16]) &
                     (ry >= r[14]) & (ry <= r[17]) &
                     (rz >= r[15]) & (rz <= r[18]);
            gx = rx * r[7] - 0.5f;
            gy = ry * r[8] - 0.5f;
            gz = rz * r[9] - 0.5f;
        }
        if (inside) {
            const int* ri = (const int*)r;
            float v = trilerp_g(sdfs + ri[19], gx, gy, gz,
                                r[10], r[11], r[12],
                                ri[20], ri[21], ri[22]);
            best = fminf(best, v);
        }
    }

    out[out_idx] = best;
}

// ---------------- fallback: round-0 validated monolithic kernel ----------------
__global__ __launch_bounds__(256) void sdf_grid_kernel(
    const float* __restrict__ sdfs,
    const int*   __restrict__ sdf_shapes,
    const int*   __restrict__ indices,
    const float* __restrict__ poses,
    const float* __restrict__ widths,
    float*       __restrict__ out,
    int total, int N, int sdf_stride)
{
    int idx = blockIdx.x * blockDim.x + threadIdx.x;
    if (idx >= total) return;
    int z = idx % GZD;
    int y = (idx / GZD) % GYD;
    int x = (idx / (GZD * GYD)) % GXD;
    int b = idx / (GZD * GYD * GXD);
    float px = GLOWER + ((float)x + 0.5f) * GSTEP;
    float py = GLOWER + ((float)y + 0.5f) * GSTEP;
    float pz = GLOWER + ((float)z + 0.5f) * GSTEP;
    float best = BIGF;
    for (int n = 0; n < N; ++n) {
        int bn = b * N + n;
        int m  = indices[bn];
        const float* pp = poses + (size_t)bn * 7;
        float tx = pp[0], ty = pp[1], tz = pp[2];
        float qx = pp[3], qy = pp[4], qz = pp[5], qw = pp[6];
        float nrm = sqrtf(qx * qx + qy * qy + qz * qz + qw * qw);
        qx = qx / nrm; qy = qy / nrm; qz = qz / nrm; qw = qw / nrm;
        float dx = px - tx, dy = py - ty, dz = pz - tz;
        float rx, ry, rz;
        rot_inv(qx, qy, qz, qw, dx, dy, dz, rx, ry, rz);
        const float* ww = widths + (size_t)bn * 3;
        float gx = rx / ww[0] - 0.5f;
        float gy = ry / ww[1] - 0.5f;
        float gz = rz / ww[2] - 0.5f;
        int SX = sdf_shapes[m * 3 + 0];
        int SY = sdf_shapes[m * 3 + 1];
        int SZ = sdf_shapes[m * 3 + 2];
        float mx = (float)(SX - 1), my = (float)(SY - 1), mz = (float)(SZ - 1);
        bool inside = (gx >= 0.0f) && (gx <= mx) &&
                      (gy >= 0.0f) && (gy <= my) &&
                      (gz >= 0.0f) && (gz <= mz);
        float fx = fminf(fmaxf(gx, 0.0f), mx);
        float fy = fminf(fmaxf(gy, 0.0f), my);
        float fz = fminf(fmaxf(gz, 0.0f), mz);
        int i0x = (int)floorf(fx), i0y = (int)floorf(fy), i0z = (int)floorf(fz);
        float frx = fx - (float)i0x, fry = fy - (float)i0y, frz = fz - (float)i0z;
        int i1x = min(i0x + 1, SX - 1);
        int i1y = min(i0y + 1, SY - 1);
        int i1z = min(i0z + 1, SZ - 1);
        const float* sd = sdfs + (size_t)m * sdf_stride;
        int b00 = (i0x * SY + i0y) * SZ;
        int b01 = (i0x * SY + i1y) * SZ;
        int b10 = (i1x * SY + i0y) * SZ;
        int b11 = (i1x * SY + i1y) * SZ;
        float v000 = sd[b00 + i0z], v001 = sd[b00 + i1z];
        float v010 = sd[b01 + i0z], v011 = sd[b01 + i1z];
        float v100 = sd[b10 + i0z], v101 = sd[b10 + i1z];
        float v110 = sd[b11 + i0z], v111 = sd[b11 + i1z];
        float wx0 = 1.0f - frx, wx1 = frx;
        float wy0 = 1.0f - fry, wy1 = fry;
        float wz0 = 1.0f - frz, wz1 = frz;
        float acc = wx0 * wy0 * wz0 * v000 + wx0 * wy0 * wz1 * v001
                  + wx0 * wy1 * wz0 * v010 + wx0 * wy1 * wz1 * v011
                  + wx1 * wy0 * wz0 * v100 + wx1 * wy0 * wz1 * v101
                  + wx1 * wy1 * wz0 * v110 + wx1 * wy1 * wz1 * v111;
        float val = inside ? acc : BIGF;
        best = fminf(best, val);
    }
    out[idx] = best;
}

extern "C" void kernel_launch(void* const* d_in, const int* in_sizes, int n_in,
                              void* d_out, int out_size, void* d_ws, size_t ws_size,
                              hipStream_t stream) {
    const float* sdfs    = (const float*)d_in[0];
    const int*   shapes  = (const int*)d_in[1];
    const int*   indices = (const int*)d_in[2];
    const float* poses   = (const float*)d_in[3];
    const float* widths  = (const float*)d_in[4];
    float*       out     = (float*)d_out;

    int M = in_sizes[1] / 3;           // sdf_shapes is (M,3)
    int sdf_stride = in_sizes[0] / M;  // elements per SDF volume
    int B = out_size / PTS_PER_B;
    int N = in_sizes[2] / B;           // indices is (B,N)
    int BN = B * N;

    size_t ws_needed = (size_t)BN * RECSZ * sizeof(float);

    if (ws_size >= ws_needed && N <= 32 && (PTS_PER_B % 256) == 0) {
        float* rec = (float*)d_ws;
        prep_v7<<<(BN + 63) / 64, 64, 0, stream>>>(
            shapes, indices, poses, widths, rec, BN, sdf_stride);
        dim3 grid(BLOCKS_PER_B, B);
        sdf_grid_v7<<<grid, 256, 0, stream>>>(sdfs, rec, out, N);
    } else {
        int total = out_size;
        int blocks = (total + 255) / 256;
        sdf_grid_kernel<<<blocks, 256, 0, stream>>>(
            sdfs, shapes, indices, poses, widths, out, total, N, sdf_stride);
    }
}

// Round 9
// 25.952 us; speedup vs baseline: 1.3407x; 1.0520x over previous
//
#include <hip/hip_runtime.h>

#define GXD 96
#define GYD 96
#define GZD 96
#define PTS_PER_B (GXD * GYD * GZD)
// cube blocks: 8x8x4 cells, 256 threads; wave = 4x4x4 cube
#define BXC 8
#define BYC 8
#define BZC 4
#define GXB (GXD / BXC)   // 12
#define GYB (GYD / BYC)   // 12
#define GZB (GZD / BZC)   // 24
#define BLOCKS_PER_B (GXB * GYB * GZB)  // 3456
#define RECSZ 56
#define BIGF 1e10f
#define GLOWER -1.2f
#define GSTEP 0.025f
#define EPS_G 1e-2f   // two-sided cull margin in g-units; |sg - g_ref| <= ~3e-4

// ---------- exact rotate: identical op order to validated rounds ----------
__device__ __forceinline__ void rot_inv(float qx, float qy, float qz, float qw,
                                        float dx, float dy, float dz,
                                        float& rx, float& ry, float& rz)
{
    float ux = -qx, uy = -qy, uz = -qz;
    float uvx = uy * dz - uz * dy;
    float uvy = uz * dx - ux * dz;
    float uvz = ux * dy - uy * dx;
    float t2x = uvx + qw * dx;
    float t2y = uvy + qw * dy;
    float t2z = uvz + qw * dz;
    rx = dx + 2.0f * (uy * t2z - uz * t2y);
    ry = dy + 2.0f * (uz * t2x - ux * t2z);
    rz = dz + 2.0f * (ux * t2y - uy * t2x);
}

__device__ __forceinline__ float next_up(float a) { return __uint_as_float(__float_as_uint(a) + 1u); }
__device__ __forceinline__ float next_dn(float a) { return __uint_as_float(__float_as_uint(a) - 1u); }

// smallest positive float a with fl(a/w) >= t   (w>0, t>0; start within ~3 ulp)
__device__ float exact_lo(float w, float t)
{
    float a = t * w;
    while (a / w < t)            a = next_up(a);
    while (next_dn(a) / w >= t)  a = next_dn(a);
    return a;
}

// largest positive float a with fl(a/w) <= L
__device__ float exact_hi(float w, float L)
{
    float a = L * w;
    while (a / w > L)            a = next_dn(a);
    while (next_up(a) / w <= L)  a = next_up(a);
    return a;
}

// record layout: identical to validated round 7
//  0-2  t      3-6  q(normalized)    7-9  invw=fl(1/w)
// 10-12 mx,my,mz=(S-1)f
// 13-15 A (exact lo)   16-18 B (exact hi)
// 19 (int) m*sdf_stride  20-22 (int) SX,SY,SZ  23 pad
// 24-26 world AABB lo    27-29 world AABB hi   30-31 pad
// 32-40 Mg = diag(invw)*R^T rows  41-43 Cg = -Mg*t - 0.5   (sg = Mg*p + Cg ~ g)
// 44-46 wideHi = mx + EPS_G   47 pad
// 48-50 narrowHi = mx - EPS_G 51-55 pad
__global__ void prep_v8(const int* __restrict__ shapes,
                        const int* __restrict__ indices,
                        const float* __restrict__ poses,
                        const float* __restrict__ widths,
                        float* __restrict__ rec,
                        int BN, int sdf_stride)
{
    int bn = blockIdx.x * blockDim.x + threadIdx.x;
    if (bn >= BN) return;
    int m = indices[bn];
    const float* pp = poses + (size_t)bn * 7;
    float tx = pp[0], ty = pp[1], tz = pp[2];
    float qx = pp[3], qy = pp[4], qz = pp[5], qw = pp[6];
    // identical op order to validated rounds -> bit-identical q
    float nrm = sqrtf(qx * qx + qy * qy + qz * qz + qw * qw);
    qx = qx / nrm; qy = qy / nrm; qz = qz / nrm; qw = qw / nrm;

    float wx = widths[bn * 3 + 0], wy = widths[bn * 3 + 1], wz = widths[bn * 3 + 2];
    int SX = shapes[m * 3 + 0], SY = shapes[m * 3 + 1], SZ = shapes[m * 3 + 2];
    float mx = (float)(SX - 1), my = (float)(SY - 1), mz = (float)(SZ - 1);

    // inside_x <=> fl(rx/w) in [0.5, mx+0.5] <=> rx in [A,B] (division monotone,
    // u-0.5 Sterbenz-exact on the decision range) — validated rounds 2-7
    float Ax = exact_lo(wx, 0.5f), Ay = exact_lo(wy, 0.5f), Az = exact_lo(wz, 0.5f);
    float Bx = exact_hi(wx, mx + 0.5f), By = exact_hi(wy, my + 0.5f), Bz = exact_hi(wz, mz + 0.5f);

    // rotation matrix R (local->world) from q
    float xx = qx * qx, yy = qy * qy, zz = qz * qz;
    float xy = qx * qy, xz = qx * qz, yz = qy * qz;
    float wqx = qw * qx, wqy = qw * qy, wqz = qw * qz;
    float R00 = 1.0f - 2.0f * (yy + zz), R01 = 2.0f * (xy - wqz), R02 = 2.0f * (xz + wqy);
    float R10 = 2.0f * (xy + wqz), R11 = 1.0f - 2.0f * (xx + zz), R12 = 2.0f * (yz - wqx);
    float R20 = 2.0f * (xz - wqy), R21 = 2.0f * (yz + wqx), R22 = 1.0f - 2.0f * (xx + yy);

    // conservative world AABB of the exact local box [A,B] (validated round 4)
    float cx = 0.5f * (Ax + Bx), cy = 0.5f * (Ay + By), cz = 0.5f * (Az + Bz);
    float hx = 0.5f * (Bx - Ax), hy = 0.5f * (By - Ay), hz = 0.5f * (Bz - Az);
    const float MARG = 2e-3f;  // >> rotation/rounding error (~1e-6)
    float wcx = tx + R00 * cx + R01 * cy + R02 * cz;
    float wcy = ty + R10 * cx + R11 * cy + R12 * cz;
    float wcz = tz + R20 * cx + R21 * cy + R22 * cz;
    float ex = fabsf(R00) * hx + fabsf(R01) * hy + fabsf(R02) * hz + MARG;
    float ey = fabsf(R10) * hx + fabsf(R11) * hy + fabsf(R12) * hz + MARG;
    float ez = fabsf(R20) * hx + fabsf(R21) * hy + fabsf(R22) * hz + MARG;

    float iwx = 1.0f / wx, iwy = 1.0f / wy, iwz = 1.0f / wz;
    // g-space affine map: sg = Mg*p + Cg, Mg rows = invw_axis * (R^T row)
    float Mg0x = iwx * R00, Mg1x = iwx * R10, Mg2x = iwx * R20;
    float Mg0y = iwy * R01, Mg1y = iwy * R11, Mg2y = iwy * R21;
    float Mg0z = iwz * R02, Mg1z = iwz * R12, Mg2z = iwz * R22;
    float Cgx = -0.5f - (Mg0x * tx + Mg1x * ty + Mg2x * tz);
    float Cgy = -0.5f - (Mg0y * tx + Mg1y * ty + Mg2y * tz);
    float Cgz = -0.5f - (Mg0z * tx + Mg1z * ty + Mg2z * tz);

    float* r = rec + (size_t)bn * RECSZ;
    r[0] = tx;  r[1] = ty;  r[2] = tz;
    r[3] = qx;  r[4] = qy;  r[5] = qz;  r[6] = qw;
    r[7] = iwx; r[8] = iwy; r[9] = iwz;
    r[10] = mx; r[11] = my; r[12] = mz;
    r[13] = Ax; r[14] = Ay; r[15] = Az;
    r[16] = Bx; r[17] = By; r[18] = Bz;
    int* ri = (int*)r;
    ri[19] = m * sdf_stride;
    ri[20] = SX; ri[21] = SY; ri[22] = SZ;
    r[23] = 0.0f;
    r[24] = wcx - ex; r[25] = wcy - ey; r[26] = wcz - ez;
    r[27] = wcx + ex; r[28] = wcy + ey; r[29] = wcz + ez;
    r[30] = 0.0f; r[31] = 0.0f;
    r[32] = Mg0x; r[33] = Mg1x; r[34] = Mg2x;
    r[35] = Mg0y; r[36] = Mg1y; r[37] = Mg2y;
    r[38] = Mg0z; r[39] = Mg1z; r[40] = Mg2z;
    r[41] = Cgx; r[42] = Cgy; r[43] = Cgz;
    r[44] = mx + EPS_G; r[45] = my + EPS_G; r[46] = mz + EPS_G;
    r[47] = 0.0f;
    r[48] = mx - EPS_G; r[49] = my - EPS_G; r[50] = mz - EPS_G;
    r[51] = 0.0f; r[52] = 0.0f; r[53] = 0.0f; r[54] = 0.0f; r[55] = 0.0f;
}

struct __attribute__((aligned(4))) F2 { float lo, hi; };

// trilerp taking g directly (validated rounds 6-7: paired-z gather, exact clamp)
__device__ __forceinline__ float trilerp_g(const float* __restrict__ sd,
                                           float gx, float gy, float gz,
                                           float mx, float my, float mz,
                                           int SX, int SY, int SZ)
{
    float fx = fminf(fmaxf(gx, 0.0f), mx);
    float fy = fminf(fmaxf(gy, 0.0f), my);
    float fz = fminf(fmaxf(gz, 0.0f), mz);
    int i0x = (int)fx, i0y = (int)fy, i0z = (int)fz;  // f>=0 -> trunc==floor
    float frx = fx - (float)i0x;
    float fry = fy - (float)i0y;
    float frz = fz - (float)i0z;
    int i1x = min(i0x + 1, SX - 1);
    int i1y = min(i0y + 1, SY - 1);

    int zb = min(i0z, max(SZ - 2, 0));
    bool at0 = (i0z == zb);

    int b00 = (i0x * SY + i0y) * SZ + zb;
    int b01 = (i0x * SY + i1y) * SZ + zb;
    int b10 = (i1x * SY + i0y) * SZ + zb;
    int b11 = (i1x * SY + i1y) * SZ + zb;

    F2 p00 = *(const F2*)(sd + b00);
    F2 p01 = *(const F2*)(sd + b01);
    F2 p10 = *(const F2*)(sd + b10);
    F2 p11 = *(const F2*)(sd + b11);

    float v000 = at0 ? p00.lo : p00.hi, v001 = p00.hi;
    float v010 = at0 ? p01.lo : p01.hi, v011 = p01.hi;
    float v100 = at0 ? p10.lo : p10.hi, v101 = p10.hi;
    float v110 = at0 ? p11.lo : p11.hi, v111 = p11.hi;

    float c00 = v000 + frz * (v001 - v000);
    float c01 = v010 + frz * (v011 - v010);
    float c10 = v100 + frz * (v101 - v100);
    float c11 = v110 + frz * (v111 - v110);
    float c0 = c00 + fry * (c01 - c00);
    float c1 = c10 + fry * (c11 - c10);
    return c0 + frx * (c1 - c0);
}

__global__ __launch_bounds__(256) void sdf_grid_v8(
    const float* __restrict__ sdfs,
    const float* __restrict__ rec,
    float* __restrict__ out,
    int N)
{
    // ---- cube decomposition: block = 8x8x4 cells, wave = 4x4x4 ----
    int bidx = blockIdx.x;                 // (xb*GYB + yb)*GZB + zb
    int b = blockIdx.y;
    int zb = bidx % GZB;
    int yb = (bidx / GZB) % GYB;
    int xb = bidx / (GZB * GYB);

    int t = threadIdx.x;
    int lane = t & 63;
    int lz = lane & 3;
    int ly = (lane >> 2) & 3;
    int lx = lane >> 4;                    // 0..3
    int wx = (t >> 6) & 1;                 // wave x half
    int wy = t >> 7;                       // wave y half

    int cx = xb * BXC + wx * 4 + lx;
    int cy = yb * BYC + wy * 4 + ly;
    int cz = zb * BZC + lz;

    float px = GLOWER + ((float)cx + 0.5f) * GSTEP;
    float py = GLOWER + ((float)cy + 0.5f) * GSTEP;
    float pz = GLOWER + ((float)cz + 0.5f) * GSTEP;

    size_t out_idx = (size_t)b * PTS_PER_B + ((size_t)cx * GYD + cy) * GZD + cz;

    // ---- per-wave ballot block mask (same AABB test as validated rounds 4-7),
    //      now against the tight 8x8x4 block cube ----
    float bxl = GLOWER + ((float)(xb * BXC) + 0.5f) * GSTEP;
    float bxh = GLOWER + ((float)(xb * BXC + BXC - 1) + 0.5f) * GSTEP;
    float byl = GLOWER + ((float)(yb * BYC) + 0.5f) * GSTEP;
    float byh = GLOWER + ((float)(yb * BYC + BYC - 1) + 0.5f) * GSTEP;
    float bzl = GLOWER + ((float)(zb * BZC) + 0.5f) * GSTEP;
    float bzh = GLOWER + ((float)(zb * BZC + BZC - 1) + 0.5f) * GSTEP;

    bool lok = false;
    if (lane < N) {
        const float* r = rec + (size_t)(b * N + lane) * RECSZ;
        lok = (bxh >= r[24]) & (bxl <= r[27]) &
              (byh >= r[25]) & (byl <= r[28]) &
              (bzh >= r[26]) & (bzl <= r[29]);
    }
    unsigned int msk = (unsigned int)__ballot(lok);

    if (msk == 0u) { out[out_idx] = BIGF; return; }

    float best = BIGF;

    for (int n = 0; n < N; ++n) {
        if (!((msk >> n) & 1u)) continue;  // whole block certainly outside SDF n

        const float* r = rec + (size_t)(b * N + n) * RECSZ;  // wave-uniform -> s_load

        // g-space affine rotate: sg ~ reference g, |err| <= ~3e-4 << EPS_G
        float sgx = fmaf(r[32], px, fmaf(r[33], py, fmaf(r[34], pz, r[41])));
        float sgy = fmaf(r[35], px, fmaf(r[36], py, fmaf(r[37], pz, r[42])));
        float sgz = fmaf(r[38], px, fmaf(r[39], py, fmaf(r[40], pz, r[43])));

        // certainly-outside: any axis beyond wide bounds
        bool wide = (sgx >= -EPS_G) & (sgx <= r[44]) &
                    (sgy >= -EPS_G) & (sgy <= r[45]) &
                    (sgz >= -EPS_G) & (sgz <= r[46]);
        if (!wide) continue;

        // certainly-inside: all axes within narrow bounds
        bool narrow = (sgx >= EPS_G) & (sgx <= r[48]) &
                      (sgy >= EPS_G) & (sgy <= r[49]) &
                      (sgz >= EPS_G) & (sgz <= r[50]);

        float gx = sgx, gy = sgy, gz = sgz;
        bool inside = true;
        if (!narrow) {
            // sliver: exact recompute, identical chain -> bit-identical decision
            float dx = px - r[0], dy = py - r[1], dz = pz - r[2];
            float rx, ry, rz;
            rot_inv(r[3], r[4], r[5], r[6], dx, dy, dz, rx, ry, rz);
            inside = (rx >= r[13]) & (rx <= r[16]) &
                     (ry >= r[14]) & (ry <= r[17]) &
                     (rz >= r[15]) & (rz <= r[18]);
            gx = rx * r[7] - 0.5f;
            gy = ry * r[8] - 0.5f;
            gz = rz * r[9] - 0.5f;
        }
        if (inside) {
            const int* ri = (const int*)r;
            float v = trilerp_g(sdfs + ri[19], gx, gy, gz,
                                r[10], r[11], r[12],
                                ri[20], ri[21], ri[22]);
            best = fminf(best, v);
        }
    }

    out[out_idx] = best;
}

// ---------------- fallback: round-0 validated monolithic kernel ----------------
__global__ __launch_bounds__(256) void sdf_grid_kernel(
    const float* __restrict__ sdfs,
    const int*   __restrict__ sdf_shapes,
    const int*   __restrict__ indices,
    const float* __restrict__ poses,
    const float* __restrict__ widths,
    float*       __restrict__ out,
    int total, int N, int sdf_stride)
{
    int idx = blockIdx.x * blockDim.x + threadIdx.x;
    if (idx >= total) return;
    int z = idx % GZD;
    int y = (idx / GZD) % GYD;
    int x = (idx / (GZD * GYD)) % GXD;
    int b = idx / (GZD * GYD * GXD);
    float px = GLOWER + ((float)x + 0.5f) * GSTEP;
    float py = GLOWER + ((float)y + 0.5f) * GSTEP;
    float pz = GLOWER + ((float)z + 0.5f) * GSTEP;
    float best = BIGF;
    for (int n = 0; n < N; ++n) {
        int bn = b * N + n;
        int m  = indices[bn];
        const float* pp = poses + (size_t)bn * 7;
        float tx = pp[0], ty = pp[1], tz = pp[2];
        float qx = pp[3], qy = pp[4], qz = pp[5], qw = pp[6];
        float nrm = sqrtf(qx * qx + qy * qy + qz * qz + qw * qw);
        qx = qx / nrm; qy = qy / nrm; qz = qz / nrm; qw = qw / nrm;
        float dx = px - tx, dy = py - ty, dz = pz - tz;
        float rx, ry, rz;
        rot_inv(qx, qy, qz, qw, dx, dy, dz, rx, ry, rz);
        const float* ww = widths + (size_t)bn * 3;
        float gx = rx / ww[0] - 0.5f;
        float gy = ry / ww[1] - 0.5f;
        float gz = rz / ww[2] - 0.5f;
        int SX = sdf_shapes[m * 3 + 0];
        int SY = sdf_shapes[m * 3 + 1];
        int SZ = sdf_shapes[m * 3 + 2];
        float mx = (float)(SX - 1), my = (float)(SY - 1), mz = (float)(SZ - 1);
        bool inside = (gx >= 0.0f) && (gx <= mx) &&
                      (gy >= 0.0f) && (gy <= my) &&
                      (gz >= 0.0f) && (gz <= mz);
        float fx = fminf(fmaxf(gx, 0.0f), mx);
        float fy = fminf(fmaxf(gy, 0.0f), my);
        float fz = fminf(fmaxf(gz, 0.0f), mz);
        int i0x = (int)floorf(fx), i0y = (int)floorf(fy), i0z = (int)floorf(fz);
        float frx = fx - (float)i0x, fry = fy - (float)i0y, frz = fz - (float)i0z;
        int i1x = min(i0x + 1, SX - 1);
        int i1y = min(i0y + 1, SY - 1);
        int i1z = min(i0z + 1, SZ - 1);
        const float* sd = sdfs + (size_t)m * sdf_stride;
        int b00 = (i0x * SY + i0y) * SZ;
        int b01 = (i0x * SY + i1y) * SZ;
        int b10 = (i1x * SY + i0y) * SZ;
        int b11 = (i1x * SY + i1y) * SZ;
        float v000 = sd[b00 + i0z], v001 = sd[b00 + i1z];
        float v010 = sd[b01 + i0z], v011 = sd[b01 + i1z];
        float v100 = sd[b10 + i0z], v101 = sd[b10 + i1z];
        float v110 = sd[b11 + i0z], v111 = sd[b11 + i1z];
        float wx0 = 1.0f - frx, wx1 = frx;
        float wy0 = 1.0f - fry, wy1 = fry;
        float wz0 = 1.0f - frz, wz1 = frz;
        float acc = wx0 * wy0 * wz0 * v000 + wx0 * wy0 * wz1 * v001
                  + wx0 * wy1 * wz0 * v010 + wx0 * wy1 * wz1 * v011
                  + wx1 * wy0 * wz0 * v100 + wx1 * wy0 * wz1 * v101
                  + wx1 * wy1 * wz0 * v110 + wx1 * wy1 * wz1 * v111;
        float val = inside ? acc : BIGF;
        best = fminf(best, val);
    }
    out[idx] = best;
}

extern "C" void kernel_launch(void* const* d_in, const int* in_sizes, int n_in,
                              void* d_out, int out_size, void* d_ws, size_t ws_size,
                              hipStream_t stream) {
    const float* sdfs    = (const float*)d_in[0];
    const int*   shapes  = (const int*)d_in[1];
    const int*   indices = (const int*)d_in[2];
    const float* poses   = (const float*)d_in[3];
    const float* widths  = (const float*)d_in[4];
    float*       out     = (float*)d_out;

    int M = in_sizes[1] / 3;           // sdf_shapes is (M,3)
    int sdf_stride = in_sizes[0] / M;  // elements per SDF volume
    int B = out_size / PTS_PER_B;
    int N = in_sizes[2] / B;           // indices is (B,N)
    int BN = B * N;

    size_t ws_needed = (size_t)BN * RECSZ * sizeof(float);

    if (ws_size >= ws_needed && N <= 32 && (PTS_PER_B % 256) == 0) {
        float* rec = (float*)d_ws;
        prep_v8<<<(BN + 63) / 64, 64, 0, stream>>>(
            shapes, indices, poses, widths, rec, BN, sdf_stride);
        dim3 grid(BLOCKS_PER_B, B);
        sdf_grid_v8<<<grid, 256, 0, stream>>>(sdfs, rec, out, N);
    } else {
        int total = out_size;
        int blocks = (total + 255) / 256;
        sdf_grid_kernel<<<blocks, 256, 0, stream>>>(
            sdfs, shapes, indices, poses, widths, out, total, N, sdf_stride);
    }
}

// Round 10
// 24.846 us; speedup vs baseline: 1.4004x; 1.0445x over previous
//
#include <hip/hip_runtime.h>

#define GXD 96
#define GYD 96
#define GZD 96
#define PTS_PER_B (GXD * GYD * GZD)
// cube blocks: 8x8x8 cells, 256 threads, 2 z-points per thread; wave = 4x4x(4x2)
#define BXC 8
#define BYC 8
#define BZC 8
#define GXB (GXD / BXC)   // 12
#define GYB (GYD / BYC)   // 12
#define GZB (GZD / BZC)   // 12
#define BLOCKS_PER_B (GXB * GYB * GZB)  // 1728
#define RECSZ 56
#define BIGF 1e10f
#define GLOWER -1.2f
#define GSTEP 0.025f
#define EPS_G 1e-2f   // two-sided cull margin in g-units; |sg - g_ref| <= ~3e-4

// ---------- exact rotate: identical op order to validated rounds ----------
__device__ __forceinline__ void rot_inv(float qx, float qy, float qz, float qw,
                                        float dx, float dy, float dz,
                                        float& rx, float& ry, float& rz)
{
    float ux = -qx, uy = -qy, uz = -qz;
    float uvx = uy * dz - uz * dy;
    float uvy = uz * dx - ux * dz;
    float uvz = ux * dy - uy * dx;
    float t2x = uvx + qw * dx;
    float t2y = uvy + qw * dy;
    float t2z = uvz + qw * dz;
    rx = dx + 2.0f * (uy * t2z - uz * t2y);
    ry = dy + 2.0f * (uz * t2x - ux * t2z);
    rz = dz + 2.0f * (ux * t2y - uy * t2x);
}

__device__ __forceinline__ float next_up(float a) { return __uint_as_float(__float_as_uint(a) + 1u); }
__device__ __forceinline__ float next_dn(float a) { return __uint_as_float(__float_as_uint(a) - 1u); }

// smallest positive float a with fl(a/w) >= t   (w>0, t>0; start within ~3 ulp)
__device__ float exact_lo(float w, float t)
{
    float a = t * w;
    while (a / w < t)            a = next_up(a);
    while (next_dn(a) / w >= t)  a = next_dn(a);
    return a;
}

// largest positive float a with fl(a/w) <= L
__device__ float exact_hi(float w, float L)
{
    float a = L * w;
    while (a / w > L)            a = next_dn(a);
    while (next_up(a) / w <= L)  a = next_up(a);
    return a;
}

// record layout: identical to validated rounds 7-8
//  0-2  t      3-6  q(normalized)    7-9  invw=fl(1/w)
// 10-12 mx,my,mz=(S-1)f
// 13-15 A (exact lo)   16-18 B (exact hi)
// 19 (int) m*sdf_stride  20-22 (int) SX,SY,SZ  23 pad
// 24-26 world AABB lo    27-29 world AABB hi   30-31 pad
// 32-40 Mg = diag(invw)*R^T rows  41-43 Cg = -Mg*t - 0.5   (sg = Mg*p + Cg ~ g)
// 44-46 wideHi = mx + EPS_G   47 pad
// 48-50 narrowHi = mx - EPS_G 51-55 pad
__global__ void prep_v9(const int* __restrict__ shapes,
                        const int* __restrict__ indices,
                        const float* __restrict__ poses,
                        const float* __restrict__ widths,
                        float* __restrict__ rec,
                        int BN, int sdf_stride)
{
    int bn = blockIdx.x * blockDim.x + threadIdx.x;
    if (bn >= BN) return;
    int m = indices[bn];
    const float* pp = poses + (size_t)bn * 7;
    float tx = pp[0], ty = pp[1], tz = pp[2];
    float qx = pp[3], qy = pp[4], qz = pp[5], qw = pp[6];
    // identical op order to validated rounds -> bit-identical q
    float nrm = sqrtf(qx * qx + qy * qy + qz * qz + qw * qw);
    qx = qx / nrm; qy = qy / nrm; qz = qz / nrm; qw = qw / nrm;

    float wx = widths[bn * 3 + 0], wy = widths[bn * 3 + 1], wz = widths[bn * 3 + 2];
    int SX = shapes[m * 3 + 0], SY = shapes[m * 3 + 1], SZ = shapes[m * 3 + 2];
    float mx = (float)(SX - 1), my = (float)(SY - 1), mz = (float)(SZ - 1);

    // inside_x <=> fl(rx/w) in [0.5, mx+0.5] <=> rx in [A,B] (division monotone,
    // u-0.5 Sterbenz-exact on the decision range) — validated rounds 2-8
    float Ax = exact_lo(wx, 0.5f), Ay = exact_lo(wy, 0.5f), Az = exact_lo(wz, 0.5f);
    float Bx = exact_hi(wx, mx + 0.5f), By = exact_hi(wy, my + 0.5f), Bz = exact_hi(wz, mz + 0.5f);

    // rotation matrix R (local->world) from q
    float xx = qx * qx, yy = qy * qy, zz = qz * qz;
    float xy = qx * qy, xz = qx * qz, yz = qy * qz;
    float wqx = qw * qx, wqy = qw * qy, wqz = qw * qz;
    float R00 = 1.0f - 2.0f * (yy + zz), R01 = 2.0f * (xy - wqz), R02 = 2.0f * (xz + wqy);
    float R10 = 2.0f * (xy + wqz), R11 = 1.0f - 2.0f * (xx + zz), R12 = 2.0f * (yz - wqx);
    float R20 = 2.0f * (xz - wqy), R21 = 2.0f * (yz + wqx), R22 = 1.0f - 2.0f * (xx + yy);

    // conservative world AABB of the exact local box [A,B] (validated round 4)
    float cx = 0.5f * (Ax + Bx), cy = 0.5f * (Ay + By), cz = 0.5f * (Az + Bz);
    float hx = 0.5f * (Bx - Ax), hy = 0.5f * (By - Ay), hz = 0.5f * (Bz - Az);
    const float MARG = 2e-3f;  // >> rotation/rounding error (~1e-6)
    float wcx = tx + R00 * cx + R01 * cy + R02 * cz;
    float wcy = ty + R10 * cx + R11 * cy + R12 * cz;
    float wcz = tz + R20 * cx + R21 * cy + R22 * cz;
    float ex = fabsf(R00) * hx + fabsf(R01) * hy + fabsf(R02) * hz + MARG;
    float ey = fabsf(R10) * hx + fabsf(R11) * hy + fabsf(R12) * hz + MARG;
    float ez = fabsf(R20) * hx + fabsf(R21) * hy + fabsf(R22) * hz + MARG;

    float iwx = 1.0f / wx, iwy = 1.0f / wy, iwz = 1.0f / wz;
    // g-space affine map: sg = Mg*p + Cg, Mg rows = invw_axis * (R^T row)
    float Mg0x = iwx * R00, Mg1x = iwx * R10, Mg2x = iwx * R20;
    float Mg0y = iwy * R01, Mg1y = iwy * R11, Mg2y = iwy * R21;
    float Mg0z = iwz * R02, Mg1z = iwz * R12, Mg2z = iwz * R22;
    float Cgx = -0.5f - (Mg0x * tx + Mg1x * ty + Mg2x * tz);
    float Cgy = -0.5f - (Mg0y * tx + Mg1y * ty + Mg2y * tz);
    float Cgz = -0.5f - (Mg0z * tx + Mg1z * ty + Mg2z * tz);

    float* r = rec + (size_t)bn * RECSZ;
    r[0] = tx;  r[1] = ty;  r[2] = tz;
    r[3] = qx;  r[4] = qy;  r[5] = qz;  r[6] = qw;
    r[7] = iwx; r[8] = iwy; r[9] = iwz;
    r[10] = mx; r[11] = my; r[12] = mz;
    r[13] = Ax; r[14] = Ay; r[15] = Az;
    r[16] = Bx; r[17] = By; r[18] = Bz;
    int* ri = (int*)r;
    ri[19] = m * sdf_stride;
    ri[20] = SX; ri[21] = SY; ri[22] = SZ;
    r[23] = 0.0f;
    r[24] = wcx - ex; r[25] = wcy - ey; r[26] = wcz - ez;
    r[27] = wcx + ex; r[28] = wcy + ey; r[29] = wcz + ez;
    r[30] = 0.0f; r[31] = 0.0f;
    r[32] = Mg0x; r[33] = Mg1x; r[34] = Mg2x;
    r[35] = Mg0y; r[36] = Mg1y; r[37] = Mg2y;
    r[38] = Mg0z; r[39] = Mg1z; r[40] = Mg2z;
    r[41] = Cgx; r[42] = Cgy; r[43] = Cgz;
    r[44] = mx + EPS_G; r[45] = my + EPS_G; r[46] = mz + EPS_G;
    r[47] = 0.0f;
    r[48] = mx - EPS_G; r[49] = my - EPS_G; r[50] = mz - EPS_G;
    r[51] = 0.0f; r[52] = 0.0f; r[53] = 0.0f; r[54] = 0.0f; r[55] = 0.0f;
}

struct __attribute__((aligned(4))) F2 { float lo, hi; };

// trilerp taking g directly (validated rounds 6-8: paired-z gather, exact clamp)
__device__ __forceinline__ float trilerp_g(const float* __restrict__ sd,
                                           float gx, float gy, float gz,
                                           float mx, float my, float mz,
                                           int SX, int SY, int SZ)
{
    float fx = fminf(fmaxf(gx, 0.0f), mx);
    float fy = fminf(fmaxf(gy, 0.0f), my);
    float fz = fminf(fmaxf(gz, 0.0f), mz);
    int i0x = (int)fx, i0y = (int)fy, i0z = (int)fz;  // f>=0 -> trunc==floor
    float frx = fx - (float)i0x;
    float fry = fy - (float)i0y;
    float frz = fz - (float)i0z;
    int i1x = min(i0x + 1, SX - 1);
    int i1y = min(i0y + 1, SY - 1);

    int zb = min(i0z, max(SZ - 2, 0));
    bool at0 = (i0z == zb);

    int b00 = (i0x * SY + i0y) * SZ + zb;
    int b01 = (i0x * SY + i1y) * SZ + zb;
    int b10 = (i1x * SY + i0y) * SZ + zb;
    int b11 = (i1x * SY + i1y) * SZ + zb;

    F2 p00 = *(const F2*)(sd + b00);
    F2 p01 = *(const F2*)(sd + b01);
    F2 p10 = *(const F2*)(sd + b10);
    F2 p11 = *(const F2*)(sd + b11);

    float v000 = at0 ? p00.lo : p00.hi, v001 = p00.hi;
    float v010 = at0 ? p01.lo : p01.hi, v011 = p01.hi;
    float v100 = at0 ? p10.lo : p10.hi, v101 = p10.hi;
    float v110 = at0 ? p11.lo : p11.hi, v111 = p11.hi;

    float c00 = v000 + frz * (v001 - v000);
    float c01 = v010 + frz * (v011 - v010);
    float c10 = v100 + frz * (v101 - v100);
    float c11 = v110 + frz * (v111 - v110);
    float c0 = c00 + fry * (c01 - c00);
    float c1 = c10 + fry * (c11 - c10);
    return c0 + frx * (c1 - c0);
}

// one point: validated wide/narrow/sliver structure from rounds 7-8
__device__ __forceinline__ void eval_point(const float* __restrict__ r,
                                           const float* __restrict__ sdfs,
                                           float sgx, float sgy, float sgz,
                                           float px, float py, float pz,
                                           float& best)
{
    // certainly-outside: any axis beyond wide bounds
    bool wide = (sgx >= -EPS_G) & (sgx <= r[44]) &
                (sgy >= -EPS_G) & (sgy <= r[45]) &
                (sgz >= -EPS_G) & (sgz <= r[46]);
    if (!wide) return;

    // certainly-inside: all axes within narrow bounds
    bool narrow = (sgx >= EPS_G) & (sgx <= r[48]) &
                  (sgy >= EPS_G) & (sgy <= r[49]) &
                  (sgz >= EPS_G) & (sgz <= r[50]);

    float gx = sgx, gy = sgy, gz = sgz;
    bool inside = true;
    if (!narrow) {
        // sliver: exact recompute, identical chain -> bit-identical decision
        float dx = px - r[0], dy = py - r[1], dz = pz - r[2];
        float rx, ry, rz;
        rot_inv(r[3], r[4], r[5], r[6], dx, dy, dz, rx, ry, rz);
        inside = (rx >= r[13]) & (rx <= r[16]) &
                 (ry >= r[14]) & (ry <= r[17]) &
                 (rz >= r[15]) & (rz <= r[18]);
        gx = rx * r[7] - 0.5f;
        gy = ry * r[8] - 0.5f;
        gz = rz * r[9] - 0.5f;
    }
    if (inside) {
        const int* ri = (const int*)r;
        float v = trilerp_g(sdfs + ri[19], gx, gy, gz,
                            r[10], r[11], r[12],
                            ri[20], ri[21], ri[22]);
        best = fminf(best, v);
    }
}

__global__ __launch_bounds__(256) void sdf_grid_v9(
    const float* __restrict__ sdfs,
    const float* __restrict__ rec,
    float* __restrict__ out,
    int N)
{
    // ---- cube decomposition: block = 8x8x8 cells, thread owns z-pair ----
    int bidx = blockIdx.x;                 // (xb*GYB + yb)*GZB + zb
    int b = blockIdx.y;
    int zb = bidx % GZB;
    int yb = (bidx / GZB) % GYB;
    int xb = bidx / (GZB * GYB);

    int t = threadIdx.x;
    int lane = t & 63;
    int lz = lane & 3;
    int ly = (lane >> 2) & 3;
    int lx = lane >> 4;                    // 0..3
    int wx = (t >> 6) & 1;
    int wy = t >> 7;

    int cx = xb * BXC + wx * 4 + lx;
    int cy = yb * BYC + wy * 4 + ly;
    int cz = zb * BZC + lz * 2;            // even; owns (cz, cz+1)

    float px  = GLOWER + ((float)cx + 0.5f) * GSTEP;
    float py  = GLOWER + ((float)cy + 0.5f) * GSTEP;
    float pz0 = GLOWER + ((float)cz + 0.5f) * GSTEP;
    float pz1 = GLOWER + ((float)(cz + 1) + 0.5f) * GSTEP;

    size_t out_idx = (size_t)b * PTS_PER_B + ((size_t)cx * GYD + cy) * GZD + cz;

    // ---- per-wave ballot block mask vs 8x8x8 block cube (validated structure) ----
    float bxl = GLOWER + ((float)(xb * BXC) + 0.5f) * GSTEP;
    float bxh = GLOWER + ((float)(xb * BXC + BXC - 1) + 0.5f) * GSTEP;
    float byl = GLOWER + ((float)(yb * BYC) + 0.5f) * GSTEP;
    float byh = GLOWER + ((float)(yb * BYC + BYC - 1) + 0.5f) * GSTEP;
    float bzl = GLOWER + ((float)(zb * BZC) + 0.5f) * GSTEP;
    float bzh = GLOWER + ((float)(zb * BZC + BZC - 1) + 0.5f) * GSTEP;

    bool lok = false;
    if (lane < N) {
        const float* r = rec + (size_t)(b * N + lane) * RECSZ;
        lok = (bxh >= r[24]) & (bxl <= r[27]) &
              (byh >= r[25]) & (byl <= r[28]) &
              (bzh >= r[26]) & (bzl <= r[29]);
    }
    unsigned int msk = (unsigned int)__ballot(lok);

    if (msk == 0u) {
        *(float2*)(out + out_idx) = make_float2(BIGF, BIGF);
        return;
    }

    float bestA = BIGF, bestB = BIGF;

    for (int n = 0; n < N; ++n) {
        if (!((msk >> n) & 1u)) continue;  // whole block certainly outside SDF n

        const float* r = rec + (size_t)(b * N + n) * RECSZ;  // wave-uniform -> s_load

        // g-space affine rotate for point A; point B = A + GSTEP * Mg[:,z]
        // (delta error ~1e-6 << EPS_G; sliver path recomputes exactly anyway)
        float sgx = fmaf(r[32], px, fmaf(r[33], py, fmaf(r[34], pz0, r[41])));
        float sgy = fmaf(r[35], px, fmaf(r[36], py, fmaf(r[37], pz0, r[42])));
        float sgz = fmaf(r[38], px, fmaf(r[39], py, fmaf(r[40], pz0, r[43])));
        float dgx = GSTEP * r[34];
        float dgy = GSTEP * r[37];
        float dgz = GSTEP * r[40];

        eval_point(r, sdfs, sgx, sgy, sgz, px, py, pz0, bestA);
        eval_point(r, sdfs, sgx + dgx, sgy + dgy, sgz + dgz, px, py, pz1, bestB);
    }

    *(float2*)(out + out_idx) = make_float2(bestA, bestB);
}

// ---------------- fallback: round-0 validated monolithic kernel ----------------
__global__ __launch_bounds__(256) void sdf_grid_kernel(
    const float* __restrict__ sdfs,
    const int*   __restrict__ sdf_shapes,
    const int*   __restrict__ indices,
    const float* __restrict__ poses,
    const float* __restrict__ widths,
    float*       __restrict__ out,
    int total, int N, int sdf_stride)
{
    int idx = blockIdx.x * blockDim.x + threadIdx.x;
    if (idx >= total) return;
    int z = idx % GZD;
    int y = (idx / GZD) % GYD;
    int x = (idx / (GZD * GYD)) % GXD;
    int b = idx / (GZD * GYD * GXD);
    float px = GLOWER + ((float)x + 0.5f) * GSTEP;
    float py = GLOWER + ((float)y + 0.5f) * GSTEP;
    float pz = GLOWER + ((float)z + 0.5f) * GSTEP;
    float best = BIGF;
    for (int n = 0; n < N; ++n) {
        int bn = b * N + n;
        int m  = indices[bn];
        const float* pp = poses + (size_t)bn * 7;
        float tx = pp[0], ty = pp[1], tz = pp[2];
        float qx = pp[3], qy = pp[4], qz = pp[5], qw = pp[6];
        float nrm = sqrtf(qx * qx + qy * qy + qz * qz + qw * qw);
        qx = qx / nrm; qy = qy / nrm; qz = qz / nrm; qw = qw / nrm;
        float dx = px - tx, dy = py - ty, dz = pz - tz;
        float rx, ry, rz;
        rot_inv(qx, qy, qz, qw, dx, dy, dz, rx, ry, rz);
        const float* ww = widths + (size_t)bn * 3;
        float gx = rx / ww[0] - 0.5f;
        float gy = ry / ww[1] - 0.5f;
        float gz = rz / ww[2] - 0.5f;
        int SX = sdf_shapes[m * 3 + 0];
        int SY = sdf_shapes[m * 3 + 1];
        int SZ = sdf_shapes[m * 3 + 2];
        float mx = (float)(SX - 1), my = (float)(SY - 1), mz = (float)(SZ - 1);
        bool inside = (gx >= 0.0f) && (gx <= mx) &&
                      (gy >= 0.0f) && (gy <= my) &&
                      (gz >= 0.0f) && (gz <= mz);
        float fx = fminf(fmaxf(gx, 0.0f), mx);
        float fy = fminf(fmaxf(gy, 0.0f), my);
        float fz = fminf(fmaxf(gz, 0.0f), mz);
        int i0x = (int)floorf(fx), i0y = (int)floorf(fy), i0z = (int)floorf(fz);
        float frx = fx - (float)i0x, fry = fy - (float)i0y, frz = fz - (float)i0z;
        int i1x = min(i0x + 1, SX - 1);
        int i1y = min(i0y + 1, SY - 1);
        int i1z = min(i0z + 1, SZ - 1);
        const float* sd = sdfs + (size_t)m * sdf_stride;
        int b00 = (i0x * SY + i0y) * SZ;
        int b01 = (i0x * SY + i1y) * SZ;
        int b10 = (i1x * SY + i0y) * SZ;
        int b11 = (i1x * SY + i1y) * SZ;
        float v000 = sd[b00 + i0z], v001 = sd[b00 + i1z];
        float v010 = sd[b01 + i0z], v011 = sd[b01 + i1z];
        float v100 = sd[b10 + i0z], v101 = sd[b10 + i1z];
        float v110 = sd[b11 + i0z], v111 = sd[b11 + i1z];
        float wx0 = 1.0f - frx, wx1 = frx;
        float wy0 = 1.0f - fry, wy1 = fry;
        float wz0 = 1.0f - frz, wz1 = frz;
        float acc = wx0 * wy0 * wz0 * v000 + wx0 * wy0 * wz1 * v001
                  + wx0 * wy1 * wz0 * v010 + wx0 * wy1 * wz1 * v011
                  + wx1 * wy0 * wz0 * v100 + wx1 * wy0 * wz1 * v101
                  + wx1 * wy1 * wz0 * v110 + wx1 * wy1 * wz1 * v111;
        float val = inside ? acc : BIGF;
        best = fminf(best, val);
    }
    out[idx] = best;
}

extern "C" void kernel_launch(void* const* d_in, const int* in_sizes, int n_in,
                              void* d_out, int out_size, void* d_ws, size_t ws_size,
                              hipStream_t stream) {
    const float* sdfs    = (const float*)d_in[0];
    const int*   shapes  = (const int*)d_in[1];
    const int*   indices = (const int*)d_in[2];
    const float* poses   = (const float*)d_in[3];
    const float* widths  = (const float*)d_in[4];
    float*       out     = (float*)d_out;

    int M = in_sizes[1] / 3;           // sdf_shapes is (M,3)
    int sdf_stride = in_sizes[0] / M;  // elements per SDF volume
    int B = out_size / PTS_PER_B;
    int N = in_sizes[2] / B;           // indices is (B,N)
    int BN = B * N;

    size_t ws_needed = (size_t)BN * RECSZ * sizeof(float);

    if (ws_size >= ws_needed && N <= 32 && (PTS_PER_B % 512) == 0) {
        float* rec = (float*)d_ws;
        prep_v9<<<(BN + 63) / 64, 64, 0, stream>>>(
            shapes, indices, poses, widths, rec, BN, sdf_stride);
        dim3 grid(BLOCKS_PER_B, B);
        sdf_grid_v9<<<grid, 256, 0, stream>>>(sdfs, rec, out, N);
    } else {
        int total = out_size;
        int blocks = (total + 255) / 256;
        sdf_grid_kernel<<<blocks, 256, 0, stream>>>(
            sdfs, shapes, indices, poses, widths, out, total, N, sdf_stride);
    }
}

// Round 11
// 24.818 us; speedup vs baseline: 1.4020x; 1.0011x over previous
//
#include <hip/hip_runtime.h>

#define GXD 96
#define GYD 96
#define GZD 96
#define PTS_PER_B (GXD * GYD * GZD)
// cube blocks: 8x8x8 cells, 256 threads, 2 z-points per thread; wave = 4x4x8 cells
#define BXC 8
#define BYC 8
#define BZC 8
#define GXB (GXD / BXC)   // 12
#define GYB (GYD / BYC)   // 12
#define GZB (GZD / BZC)   // 12
#define BLOCKS_PER_B (GXB * GYB * GZB)  // 1728
#define RECSZ 56
#define BIGF 1e10f
#define GLOWER -1.2f
#define GSTEP 0.025f
#define EPS_G 1e-2f   // two-sided cull margin in g-units; |sg - g_ref| <= ~3e-4

// ---------- exact rotate: identical op order to validated rounds ----------
__device__ __forceinline__ void rot_inv(float qx, float qy, float qz, float qw,
                                        float dx, float dy, float dz,
                                        float& rx, float& ry, float& rz)
{
    float ux = -qx, uy = -qy, uz = -qz;
    float uvx = uy * dz - uz * dy;
    float uvy = uz * dx - ux * dz;
    float uvz = ux * dy - uy * dx;
    float t2x = uvx + qw * dx;
    float t2y = uvy + qw * dy;
    float t2z = uvz + qw * dz;
    rx = dx + 2.0f * (uy * t2z - uz * t2y);
    ry = dy + 2.0f * (uz * t2x - ux * t2z);
    rz = dz + 2.0f * (ux * t2y - uy * t2x);
}

__device__ __forceinline__ float next_up(float a) { return __uint_as_float(__float_as_uint(a) + 1u); }
__device__ __forceinline__ float next_dn(float a) { return __uint_as_float(__float_as_uint(a) - 1u); }

// smallest positive float a with fl(a/w) >= t   (w>0, t>0; start within ~3 ulp)
__device__ __forceinline__ float exact_lo(float w, float t)
{
    float a = t * w;
    while (a / w < t)            a = next_up(a);
    while (next_dn(a) / w >= t)  a = next_dn(a);
    return a;
}

// largest positive float a with fl(a/w) <= L
__device__ __forceinline__ float exact_hi(float w, float L)
{
    float a = L * w;
    while (a / w > L)            a = next_dn(a);
    while (next_up(a) / w <= L)  a = next_up(a);
    return a;
}

// record layout: identical to validated rounds 7-9
//  0-2  t      3-6  q(normalized)    7-9  invw=fl(1/w)
// 10-12 mx,my,mz=(S-1)f
// 13-15 A (exact lo)   16-18 B (exact hi)
// 19 (int) m*sdf_stride  20-22 (int) SX,SY,SZ  23 pad
// 24-26 world AABB lo    27-29 world AABB hi   30-31 pad
// 32-40 Mg = diag(invw)*R^T rows  41-43 Cg = -Mg*t - 0.5   (sg = Mg*p + Cg ~ g)
// 44-46 wideHi = mx + EPS_G   47 pad
// 48-50 narrowHi = mx - EPS_G 51-55 pad
//
// Parallelized by (bn, bound): 6 threads per bn. slot = tid%6:
//   slot 0 -> exact A.x (r[13]) + ALL shared fields
//   slot 1 -> exact B.x (r[16]);  slot 2/3 -> A.y/B.y;  slot 4/5 -> A.z/B.z
// Disjoint writes, no sync needed. World AABB uses approximate 0.5*w /
// (m+0.5)*w extents (within ulps of exact A/B) -- legitimate: AABB is a
// conservative cull with MARG=2e-3 >> 1e-7. Exact A/B (decision path) are
// still the bisected values.
__global__ void prep_v10(const int* __restrict__ shapes,
                         const int* __restrict__ indices,
                         const float* __restrict__ poses,
                         const float* __restrict__ widths,
                         float* __restrict__ rec,
                         int BN, int sdf_stride)
{
    int tid = blockIdx.x * blockDim.x + threadIdx.x;
    int bn = tid / 6;
    int slot = tid % 6;
    if (bn >= BN) return;
    int m = indices[bn];
    const float* pp = poses + (size_t)bn * 7;
    float tx = pp[0], ty = pp[1], tz = pp[2];
    float qx = pp[3], qy = pp[4], qz = pp[5], qw = pp[6];
    // identical op order to validated rounds -> bit-identical q
    float nrm = sqrtf(qx * qx + qy * qy + qz * qz + qw * qw);
    qx = qx / nrm; qy = qy / nrm; qz = qz / nrm; qw = qw / nrm;

    float wx = widths[bn * 3 + 0], wy = widths[bn * 3 + 1], wz = widths[bn * 3 + 2];
    int SX = shapes[m * 3 + 0], SY = shapes[m * 3 + 1], SZ = shapes[m * 3 + 2];
    float mx = (float)(SX - 1), my = (float)(SY - 1), mz = (float)(SZ - 1);

    float* r = rec + (size_t)bn * RECSZ;

    int axis = slot >> 1;
    int hi = slot & 1;
    float wa = (axis == 0) ? wx : ((axis == 1) ? wy : wz);
    float ma = (axis == 0) ? mx : ((axis == 1) ? my : mz);

    // inside_a <=> fl(ra/w) in [0.5, ma+0.5] <=> ra in [A,B] (division monotone,
    // u-0.5 Sterbenz-exact on the decision range) — validated rounds 2-9
    if (!hi) r[13 + axis] = exact_lo(wa, 0.5f);
    else     r[16 + axis] = exact_hi(wa, ma + 0.5f);

    if (slot != 0) return;

    // ---- slot 0: all shared fields ----
    // rotation matrix R (local->world) from q
    float xx = qx * qx, yy = qy * qy, zz = qz * qz;
    float xy = qx * qy, xz = qx * qz, yz = qy * qz;
    float wqx = qw * qx, wqy = qw * qy, wqz = qw * qz;
    float R00 = 1.0f - 2.0f * (yy + zz), R01 = 2.0f * (xy - wqz), R02 = 2.0f * (xz + wqy);
    float R10 = 2.0f * (xy + wqz), R11 = 1.0f - 2.0f * (xx + zz), R12 = 2.0f * (yz - wqx);
    float R20 = 2.0f * (xz - wqy), R21 = 2.0f * (yz + wqx), R22 = 1.0f - 2.0f * (xx + yy);

    // approximate local box for the conservative world AABB (MARG absorbs ulps)
    float Axa = 0.5f * wx, Aya = 0.5f * wy, Aza = 0.5f * wz;
    float Bxa = (mx + 0.5f) * wx, Bya = (my + 0.5f) * wy, Bza = (mz + 0.5f) * wz;
    float cx = 0.5f * (Axa + Bxa), cy = 0.5f * (Aya + Bya), cz = 0.5f * (Aza + Bza);
    float hx = 0.5f * (Bxa - Axa), hy = 0.5f * (Bya - Aya), hz = 0.5f * (Bza - Aza);
    const float MARG = 2e-3f;  // >> rotation/rounding error (~1e-6)
    float wcx = tx + R00 * cx + R01 * cy + R02 * cz;
    float wcy = ty + R10 * cx + R11 * cy + R12 * cz;
    float wcz = tz + R20 * cx + R21 * cy + R22 * cz;
    float ex = fabsf(R00) * hx + fabsf(R01) * hy + fabsf(R02) * hz + MARG;
    float ey = fabsf(R10) * hx + fabsf(R11) * hy + fabsf(R12) * hz + MARG;
    float ez = fabsf(R20) * hx + fabsf(R21) * hy + fabsf(R22) * hz + MARG;

    float iwx = 1.0f / wx, iwy = 1.0f / wy, iwz = 1.0f / wz;
    // g-space affine map: sg = Mg*p + Cg, Mg rows = invw_axis * (R^T row)
    float Mg0x = iwx * R00, Mg1x = iwx * R10, Mg2x = iwx * R20;
    float Mg0y = iwy * R01, Mg1y = iwy * R11, Mg2y = iwy * R21;
    float Mg0z = iwz * R02, Mg1z = iwz * R12, Mg2z = iwz * R22;
    float Cgx = -0.5f - (Mg0x * tx + Mg1x * ty + Mg2x * tz);
    float Cgy = -0.5f - (Mg0y * tx + Mg1y * ty + Mg2y * tz);
    float Cgz = -0.5f - (Mg0z * tx + Mg1z * ty + Mg2z * tz);

    r[0] = tx;  r[1] = ty;  r[2] = tz;
    r[3] = qx;  r[4] = qy;  r[5] = qz;  r[6] = qw;
    r[7] = iwx; r[8] = iwy; r[9] = iwz;
    r[10] = mx; r[11] = my; r[12] = mz;
    int* ri = (int*)r;
    ri[19] = m * sdf_stride;
    ri[20] = SX; ri[21] = SY; ri[22] = SZ;
    r[23] = 0.0f;
    r[24] = wcx - ex; r[25] = wcy - ey; r[26] = wcz - ez;
    r[27] = wcx + ex; r[28] = wcy + ey; r[29] = wcz + ez;
    r[30] = 0.0f; r[31] = 0.0f;
    r[32] = Mg0x; r[33] = Mg1x; r[34] = Mg2x;
    r[35] = Mg0y; r[36] = Mg1y; r[37] = Mg2y;
    r[38] = Mg0z; r[39] = Mg1z; r[40] = Mg2z;
    r[41] = Cgx; r[42] = Cgy; r[43] = Cgz;
    r[44] = mx + EPS_G; r[45] = my + EPS_G; r[46] = mz + EPS_G;
    r[47] = 0.0f;
    r[48] = mx - EPS_G; r[49] = my - EPS_G; r[50] = mz - EPS_G;
    r[51] = 0.0f; r[52] = 0.0f; r[53] = 0.0f; r[54] = 0.0f; r[55] = 0.0f;
}

struct __attribute__((aligned(4))) F2 { float lo, hi; };

// trilerp taking g directly (validated rounds 6-9: paired-z gather, exact clamp)
__device__ __forceinline__ float trilerp_g(const float* __restrict__ sd,
                                           float gx, float gy, float gz,
                                           float mx, float my, float mz,
                                           int SX, int SY, int SZ)
{
    float fx = fminf(fmaxf(gx, 0.0f), mx);
    float fy = fminf(fmaxf(gy, 0.0f), my);
    float fz = fminf(fmaxf(gz, 0.0f), mz);
    int i0x = (int)fx, i0y = (int)fy, i0z = (int)fz;  // f>=0 -> trunc==floor
    float frx = fx - (float)i0x;
    float fry = fy - (float)i0y;
    float frz = fz - (float)i0z;
    int i1x = min(i0x + 1, SX - 1);
    int i1y = min(i0y + 1, SY - 1);

    int zb = min(i0z, max(SZ - 2, 0));
    bool at0 = (i0z == zb);

    int b00 = (i0x * SY + i0y) * SZ + zb;
    int b01 = (i0x * SY + i1y) * SZ + zb;
    int b10 = (i1x * SY + i0y) * SZ + zb;
    int b11 = (i1x * SY + i1y) * SZ + zb;

    F2 p00 = *(const F2*)(sd + b00);
    F2 p01 = *(const F2*)(sd + b01);
    F2 p10 = *(const F2*)(sd + b10);
    F2 p11 = *(const F2*)(sd + b11);

    float v000 = at0 ? p00.lo : p00.hi, v001 = p00.hi;
    float v010 = at0 ? p01.lo : p01.hi, v011 = p01.hi;
    float v100 = at0 ? p10.lo : p10.hi, v101 = p10.hi;
    float v110 = at0 ? p11.lo : p11.hi, v111 = p11.hi;

    float c00 = v000 + frz * (v001 - v000);
    float c01 = v010 + frz * (v011 - v010);
    float c10 = v100 + frz * (v101 - v100);
    float c11 = v110 + frz * (v111 - v110);
    float c0 = c00 + fry * (c01 - c00);
    float c1 = c10 + fry * (c11 - c10);
    return c0 + frx * (c1 - c0);
}

// one point: validated wide/narrow/sliver structure from rounds 7-9
__device__ __forceinline__ void eval_point(const float* __restrict__ r,
                                           const float* __restrict__ sdfs,
                                           float sgx, float sgy, float sgz,
                                           float px, float py, float pz,
                                           float& best)
{
    // certainly-outside: any axis beyond wide bounds
    bool wide = (sgx >= -EPS_G) & (sgx <= r[44]) &
                (sgy >= -EPS_G) & (sgy <= r[45]) &
                (sgz >= -EPS_G) & (sgz <= r[46]);
    if (!wide) return;

    // certainly-inside: all axes within narrow bounds
    bool narrow = (sgx >= EPS_G) & (sgx <= r[48]) &
                  (sgy >= EPS_G) & (sgy <= r[49]) &
                  (sgz >= EPS_G) & (sgz <= r[50]);

    float gx = sgx, gy = sgy, gz = sgz;
    bool inside = true;
    if (!narrow) {
        // sliver: exact recompute, identical chain -> bit-identical decision
        float dx = px - r[0], dy = py - r[1], dz = pz - r[2];
        float rx, ry, rz;
        rot_inv(r[3], r[4], r[5], r[6], dx, dy, dz, rx, ry, rz);
        inside = (rx >= r[13]) & (rx <= r[16]) &
                 (ry >= r[14]) & (ry <= r[17]) &
                 (rz >= r[15]) & (rz <= r[18]);
        gx = rx * r[7] - 0.5f;
        gy = ry * r[8] - 0.5f;
        gz = rz * r[9] - 0.5f;
    }
    if (inside) {
        const int* ri = (const int*)r;
        float v = trilerp_g(sdfs + ri[19], gx, gy, gz,
                            r[10], r[11], r[12],
                            ri[20], ri[21], ri[22]);
        best = fminf(best, v);
    }
}

__global__ __launch_bounds__(256) void sdf_grid_v10(
    const float* __restrict__ sdfs,
    const float* __restrict__ rec,
    float* __restrict__ out,
    int N)
{
    // ---- cube decomposition: block = 8x8x8 cells, thread owns z-pair ----
    int bidx = blockIdx.x;                 // (xb*GYB + yb)*GZB + zb
    int b = blockIdx.y;
    int zb = bidx % GZB;
    int yb = (bidx / GZB) % GYB;
    int xb = bidx / (GZB * GYB);

    int t = threadIdx.x;
    int lane = t & 63;
    int lz = lane & 3;
    int ly = (lane >> 2) & 3;
    int lx = lane >> 4;                    // 0..3
    int wvx = (t >> 6) & 1;
    int wvy = t >> 7;

    int x0 = xb * BXC + wvx * 4;           // wave cube origin: 4x4x8 cells
    int y0 = yb * BYC + wvy * 4;
    int z0 = zb * BZC;

    int cx = x0 + lx;
    int cy = y0 + ly;
    int cz = z0 + lz * 2;                  // even; owns (cz, cz+1)

    float px  = GLOWER + ((float)cx + 0.5f) * GSTEP;
    float py  = GLOWER + ((float)cy + 0.5f) * GSTEP;
    float pz0 = GLOWER + ((float)cz + 0.5f) * GSTEP;
    float pz1 = GLOWER + ((float)(cz + 1) + 0.5f) * GSTEP;

    size_t out_idx = (size_t)b * PTS_PER_B + ((size_t)cx * GYD + cy) * GZD + cz;

    // ---- per-wave ballot mask vs the WAVE's own 4x4x8 cube (tighter than block) ----
    float bxl = GLOWER + ((float)x0 + 0.5f) * GSTEP;
    float bxh = GLOWER + ((float)(x0 + 3) + 0.5f) * GSTEP;
    float byl = GLOWER + ((float)y0 + 0.5f) * GSTEP;
    float byh = GLOWER + ((float)(y0 + 3) + 0.5f) * GSTEP;
    float bzl = GLOWER + ((float)z0 + 0.5f) * GSTEP;
    float bzh = GLOWER + ((float)(z0 + BZC - 1) + 0.5f) * GSTEP;

    bool lok = false;
    if (lane < N) {
        const float* r = rec + (size_t)(b * N + lane) * RECSZ;
        lok = (bxh >= r[24]) & (bxl <= r[27]) &
              (byh >= r[25]) & (byl <= r[28]) &
              (bzh >= r[26]) & (bzl <= r[29]);
    }
    unsigned int msk = (unsigned int)__ballot(lok);

    if (msk == 0u) {
        *(float2*)(out + out_idx) = make_float2(BIGF, BIGF);
        return;
    }

    float bestA = BIGF, bestB = BIGF;

    for (int n = 0; n < N; ++n) {
        if (!((msk >> n) & 1u)) continue;  // whole wave certainly outside SDF n

        const float* r = rec + (size_t)(b * N + n) * RECSZ;  // wave-uniform -> s_load

        // g-space affine rotate for point A; point B = A + GSTEP * Mg[:,z]
        // (delta error ~1e-6 << EPS_G; sliver path recomputes exactly anyway)
        float sgx = fmaf(r[32], px, fmaf(r[33], py, fmaf(r[34], pz0, r[41])));
        float sgy = fmaf(r[35], px, fmaf(r[36], py, fmaf(r[37], pz0, r[42])));
        float sgz = fmaf(r[38], px, fmaf(r[39], py, fmaf(r[40], pz0, r[43])));
        float dgx = GSTEP * r[34];
        float dgy = GSTEP * r[37];
        float dgz = GSTEP * r[40];

        eval_point(r, sdfs, sgx, sgy, sgz, px, py, pz0, bestA);
        eval_point(r, sdfs, sgx + dgx, sgy + dgy, sgz + dgz, px, py, pz1, bestB);
    }

    *(float2*)(out + out_idx) = make_float2(bestA, bestB);
}

// ---------------- fallback: round-0 validated monolithic kernel ----------------
__global__ __launch_bounds__(256) void sdf_grid_kernel(
    const float* __restrict__ sdfs,
    const int*   __restrict__ sdf_shapes,
    const int*   __restrict__ indices,
    const float* __restrict__ poses,
    const float* __restrict__ widths,
    float*       __restrict__ out,
    int total, int N, int sdf_stride)
{
    int idx = blockIdx.x * blockDim.x + threadIdx.x;
    if (idx >= total) return;
    int z = idx % GZD;
    int y = (idx / GZD) % GYD;
    int x = (idx / (GZD * GYD)) % GXD;
    int b = idx / (GZD * GYD * GXD);
    float px = GLOWER + ((float)x + 0.5f) * GSTEP;
    float py = GLOWER + ((float)y + 0.5f) * GSTEP;
    float pz = GLOWER + ((float)z + 0.5f) * GSTEP;
    float best = BIGF;
    for (int n = 0; n < N; ++n) {
        int bn = b * N + n;
        int m  = indices[bn];
        const float* pp = poses + (size_t)bn * 7;
        float tx = pp[0], ty = pp[1], tz = pp[2];
        float qx = pp[3], qy = pp[4], qz = pp[5], qw = pp[6];
        float nrm = sqrtf(qx * qx + qy * qy + qz * qz + qw * qw);
        qx = qx / nrm; qy = qy / nrm; qz = qz / nrm; qw = qw / nrm;
        float dx = px - tx, dy = py - ty, dz = pz - tz;
        float rx, ry, rz;
        rot_inv(qx, qy, qz, qw, dx, dy, dz, rx, ry, rz);
        const float* ww = widths + (size_t)bn * 3;
        float gx = rx / ww[0] - 0.5f;
        float gy = ry / ww[1] - 0.5f;
        float gz = rz / ww[2] - 0.5f;
        int SX = sdf_shapes[m * 3 + 0];
        int SY = sdf_shapes[m * 3 + 1];
        int SZ = sdf_shapes[m * 3 + 2];
        float mx = (float)(SX - 1), my = (float)(SY - 1), mz = (float)(SZ - 1);
        bool inside = (gx >= 0.0f) && (gx <= mx) &&
                      (gy >= 0.0f) && (gy <= my) &&
                      (gz >= 0.0f) && (gz <= mz);
        float fx = fminf(fmaxf(gx, 0.0f), mx);
        float fy = fminf(fmaxf(gy, 0.0f), my);
        float fz = fminf(fmaxf(gz, 0.0f), mz);
        int i0x = (int)floorf(fx), i0y = (int)floorf(fy), i0z = (int)floorf(fz);
        float frx = fx - (float)i0x, fry = fy - (float)i0y, frz = fz - (float)i0z;
        int i1x = min(i0x + 1, SX - 1);
        int i1y = min(i0y + 1, SY - 1);
        int i1z = min(i0z + 1, SZ - 1);
        const float* sd = sdfs + (size_t)m * sdf_stride;
        int b00 = (i0x * SY + i0y) * SZ;
        int b01 = (i0x * SY + i1y) * SZ;
        int b10 = (i1x * SY + i0y) * SZ;
        int b11 = (i1x * SY + i1y) * SZ;
        float v000 = sd[b00 + i0z], v001 = sd[b00 + i1z];
        float v010 = sd[b01 + i0z], v011 = sd[b01 + i1z];
        float v100 = sd[b10 + i0z], v101 = sd[b10 + i1z];
        float v110 = sd[b11 + i0z], v111 = sd[b11 + i1z];
        float wx0 = 1.0f - frx, wx1 = frx;
        float wy0 = 1.0f - fry, wy1 = fry;
        float wz0 = 1.0f - frz, wz1 = frz;
        float acc = wx0 * wy0 * wz0 * v000 + wx0 * wy0 * wz1 * v001
                  + wx0 * wy1 * wz0 * v010 + wx0 * wy1 * wz1 * v011
                  + wx1 * wy0 * wz0 * v100 + wx1 * wy0 * wz1 * v101
                  + wx1 * wy1 * wz0 * v110 + wx1 * wy1 * wz1 * v111;
        float val = inside ? acc : BIGF;
        best = fminf(best, val);
    }
    out[idx] = best;
}

extern "C" void kernel_launch(void* const* d_in, const int* in_sizes, int n_in,
                              void* d_out, int out_size, void* d_ws, size_t ws_size,
                              hipStream_t stream) {
    const float* sdfs    = (const float*)d_in[0];
    const int*   shapes  = (const int*)d_in[1];
    const int*   indices = (const int*)d_in[2];
    const float* poses   = (const float*)d_in[3];
    const float* widths  = (const float*)d_in[4];
    float*       out     = (float*)d_out;

    int M = in_sizes[1] / 3;           // sdf_shapes is (M,3)
    int sdf_stride = in_sizes[0] / M;  // elements per SDF volume
    int B = out_size / PTS_PER_B;
    int N = in_sizes[2] / B;           // indices is (B,N)
    int BN = B * N;

    size_t ws_needed = (size_t)BN * RECSZ * sizeof(float);

    if (ws_size >= ws_needed && N <= 32 && (PTS_PER_B % 512) == 0) {
        float* rec = (float*)d_ws;
        int ptot = BN * 6;
        prep_v10<<<(ptot + 127) / 128, 128, 0, stream>>>(
            shapes, indices, poses, widths, rec, BN, sdf_stride);
        dim3 grid(BLOCKS_PER_B, B);
        sdf_grid_v10<<<grid, 256, 0, stream>>>(sdfs, rec, out, N);
    } else {
        int total = out_size;
        int blocks = (total + 255) / 256;
        sdf_grid_kernel<<<blocks, 256, 0, stream>>>(
            sdfs, shapes, indices, poses, widths, out, total, N, sdf_stride);
    }
}

// Round 12
// 23.844 us; speedup vs baseline: 1.4592x; 1.0408x over previous
//
#include <hip/hip_runtime.h>

#define GXD 96
#define GYD 96
#define GZD 96
#define PTS_PER_B (GXD * GYD * GZD)
// block = 8x8x8 cells, 128 threads, 4 z-points per thread; wave = 8x8x4 cells
#define BXC 8
#define BYC 8
#define BZC 8
#define GXB (GXD / BXC)   // 12
#define GYB (GYD / BYC)   // 12
#define GZB (GZD / BZC)   // 12
#define BLOCKS_PER_B (GXB * GYB * GZB)  // 1728
#define MAXN 16
#define RECL 44           // floats per LDS record
#define BIGF 1e10f
#define GLOWER -1.2f
#define GSTEP 0.025f
#define EPS_G 1e-2f   // two-sided cull margin in g-units; |sg - g_ref| <= ~3e-4

// LDS record layout (floats unless noted):
//  0-2  t      3-6  q(normalized)   7-9  w (raw widths, for exact sliver division)
// 10-12 mx,my,mz=(S-1)f
// 13-21 Mg = diag(1/w)*R^T rows (Mg0x,Mg1x,Mg2x, Mg0y,Mg1y,Mg2y, Mg0z,Mg1z,Mg2z)
// 22-24 Cg = -Mg*t - 0.5          (sg = Mg*p + Cg ~ reference g)
// 25-27 wideHi   = m + EPS_G
// 28-30 narrowHi = m - EPS_G
// 31-33 world AABB lo   34-36 world AABB hi
// 37 (int) m*sdf_stride  38-40 (int) SX,SY,SZ
// 41-43 pad

// ---------- exact rotate: identical op order to validated rounds ----------
__device__ __forceinline__ void rot_inv(float qx, float qy, float qz, float qw,
                                        float dx, float dy, float dz,
                                        float& rx, float& ry, float& rz)
{
    float ux = -qx, uy = -qy, uz = -qz;
    float uvx = uy * dz - uz * dy;
    float uvy = uz * dx - ux * dz;
    float uvz = ux * dy - uy * dx;
    float t2x = uvx + qw * dx;
    float t2y = uvy + qw * dy;
    float t2z = uvz + qw * dz;
    rx = dx + 2.0f * (uy * t2z - uz * t2y);
    ry = dy + 2.0f * (uz * t2x - ux * t2z);
    rz = dz + 2.0f * (ux * t2y - uy * t2x);
}

struct __attribute__((aligned(4))) F2 { float lo, hi; };

// trilerp taking g directly (validated rounds 6-10: paired-z gather, exact clamp)
__device__ __forceinline__ float trilerp_g(const float* __restrict__ sd,
                                           float gx, float gy, float gz,
                                           float mx, float my, float mz,
                                           int SX, int SY, int SZ)
{
    float fx = fminf(fmaxf(gx, 0.0f), mx);
    float fy = fminf(fmaxf(gy, 0.0f), my);
    float fz = fminf(fmaxf(gz, 0.0f), mz);
    int i0x = (int)fx, i0y = (int)fy, i0z = (int)fz;  // f>=0 -> trunc==floor
    float frx = fx - (float)i0x;
    float fry = fy - (float)i0y;
    float frz = fz - (float)i0z;
    int i1x = min(i0x + 1, SX - 1);
    int i1y = min(i0y + 1, SY - 1);

    int zb = min(i0z, max(SZ - 2, 0));
    bool at0 = (i0z == zb);

    int b00 = (i0x * SY + i0y) * SZ + zb;
    int b01 = (i0x * SY + i1y) * SZ + zb;
    int b10 = (i1x * SY + i0y) * SZ + zb;
    int b11 = (i1x * SY + i1y) * SZ + zb;

    F2 p00 = *(const F2*)(sd + b00);
    F2 p01 = *(const F2*)(sd + b01);
    F2 p10 = *(const F2*)(sd + b10);
    F2 p11 = *(const F2*)(sd + b11);

    float v000 = at0 ? p00.lo : p00.hi, v001 = p00.hi;
    float v010 = at0 ? p01.lo : p01.hi, v011 = p01.hi;
    float v100 = at0 ? p10.lo : p10.hi, v101 = p10.hi;
    float v110 = at0 ? p11.lo : p11.hi, v111 = p11.hi;

    float c00 = v000 + frz * (v001 - v000);
    float c01 = v010 + frz * (v011 - v010);
    float c10 = v100 + frz * (v101 - v100);
    float c11 = v110 + frz * (v111 - v110);
    float c0 = c00 + fry * (c01 - c00);
    float c1 = c10 + fry * (c11 - c10);
    return c0 + frx * (c1 - c0);
}

// one point: wide/narrow two-sided margin (validated r7-r10); sliver decision is
// the REFERENCE chain verbatim (rot_inv + IEEE division + [0,m] compare) ->
// bit-identical to the round-0 validated kernel by construction.
__device__ __forceinline__ void eval_point(const float* __restrict__ r,
                                           const float* __restrict__ sdfs,
                                           float sgx, float sgy, float sgz,
                                           float px, float py, float pz,
                                           float& best)
{
    bool wide = (sgx >= -EPS_G) & (sgx <= r[25]) &
                (sgy >= -EPS_G) & (sgy <= r[26]) &
                (sgz >= -EPS_G) & (sgz <= r[27]);
    if (!wide) return;

    bool narrow = (sgx >= EPS_G) & (sgx <= r[28]) &
                  (sgy >= EPS_G) & (sgy <= r[29]) &
                  (sgz >= EPS_G) & (sgz <= r[30]);

    float gx = sgx, gy = sgy, gz = sgz;
    bool inside = true;
    if (!narrow) {
        // sliver: exact reference chain -> bit-identical decision
        float dx = px - r[0], dy = py - r[1], dz = pz - r[2];
        float rx, ry, rz;
        rot_inv(r[3], r[4], r[5], r[6], dx, dy, dz, rx, ry, rz);
        gx = rx / r[7] - 0.5f;
        gy = ry / r[8] - 0.5f;
        gz = rz / r[9] - 0.5f;
        inside = (gx >= 0.0f) & (gx <= r[10]) &
                 (gy >= 0.0f) & (gy <= r[11]) &
                 (gz >= 0.0f) & (gz <= r[12]);
    }
    if (inside) {
        const int* ri = (const int*)r;
        float v = trilerp_g(sdfs + ri[37], gx, gy, gz,
                            r[10], r[11], r[12],
                            ri[38], ri[39], ri[40]);
        best = fminf(best, v);
    }
}

__global__ __launch_bounds__(128) void sdf_grid_v11(
    const float* __restrict__ sdfs,
    const int*   __restrict__ shapes,
    const int*   __restrict__ indices,
    const float* __restrict__ poses,
    const float* __restrict__ widths,
    float*       __restrict__ out,
    int N, int sdf_stride)
{
    __shared__ float srec[MAXN][RECL];

    int bidx = blockIdx.x;                 // (xb*GYB + yb)*GZB + zb
    int b = blockIdx.y;
    int zbk = bidx % GZB;
    int ybk = (bidx / GZB) % GYB;
    int xbk = bidx / (GZB * GYB);

    int t = threadIdx.x;

    // ---- in-block prep: thread n (< N) builds record n for batch b ----
    if (t < N) {
        int bn = b * N + t;
        int m = indices[bn];
        const float* pp = poses + (size_t)bn * 7;
        float tx = pp[0], ty = pp[1], tz = pp[2];
        float qx = pp[3], qy = pp[4], qz = pp[5], qw = pp[6];
        // identical op order to validated rounds -> bit-identical q
        float nrm = sqrtf(qx * qx + qy * qy + qz * qz + qw * qw);
        qx = qx / nrm; qy = qy / nrm; qz = qz / nrm; qw = qw / nrm;

        float wx = widths[bn * 3 + 0], wy = widths[bn * 3 + 1], wz = widths[bn * 3 + 2];
        int SX = shapes[m * 3 + 0], SY = shapes[m * 3 + 1], SZ = shapes[m * 3 + 2];
        float mx = (float)(SX - 1), my = (float)(SY - 1), mz = (float)(SZ - 1);

        // rotation matrix R (local->world) from q
        float xx = qx * qx, yy = qy * qy, zz = qz * qz;
        float xy = qx * qy, xz = qx * qz, yz = qy * qz;
        float wqx = qw * qx, wqy = qw * qy, wqz = qw * qz;
        float R00 = 1.0f - 2.0f * (yy + zz), R01 = 2.0f * (xy - wqz), R02 = 2.0f * (xz + wqy);
        float R10 = 2.0f * (xy + wqz), R11 = 1.0f - 2.0f * (xx + zz), R12 = 2.0f * (yz - wqx);
        float R20 = 2.0f * (xz - wqy), R21 = 2.0f * (yz + wqx), R22 = 1.0f - 2.0f * (xx + yy);

        // conservative world AABB (approx extents; MARG >> all rounding) - r10-validated
        float Axa = 0.5f * wx, Aya = 0.5f * wy, Aza = 0.5f * wz;
        float Bxa = (mx + 0.5f) * wx, Bya = (my + 0.5f) * wy, Bza = (mz + 0.5f) * wz;
        float cx = 0.5f * (Axa + Bxa), cy = 0.5f * (Aya + Bya), cz = 0.5f * (Aza + Bza);
        float hx = 0.5f * (Bxa - Axa), hy = 0.5f * (Bya - Aya), hz = 0.5f * (Bza - Aza);
        const float MARG = 2e-3f;
        float wcx = tx + R00 * cx + R01 * cy + R02 * cz;
        float wcy = ty + R10 * cx + R11 * cy + R12 * cz;
        float wcz = tz + R20 * cx + R21 * cy + R22 * cz;
        float ex = fabsf(R00) * hx + fabsf(R01) * hy + fabsf(R02) * hz + MARG;
        float ey = fabsf(R10) * hx + fabsf(R11) * hy + fabsf(R12) * hz + MARG;
        float ez = fabsf(R20) * hx + fabsf(R21) * hy + fabsf(R22) * hz + MARG;

        float iwx = 1.0f / wx, iwy = 1.0f / wy, iwz = 1.0f / wz;
        float Mg0x = iwx * R00, Mg1x = iwx * R10, Mg2x = iwx * R20;
        float Mg0y = iwy * R01, Mg1y = iwy * R11, Mg2y = iwy * R21;
        float Mg0z = iwz * R02, Mg1z = iwz * R12, Mg2z = iwz * R22;
        float Cgx = -0.5f - (Mg0x * tx + Mg1x * ty + Mg2x * tz);
        float Cgy = -0.5f - (Mg0y * tx + Mg1y * ty + Mg2y * tz);
        float Cgz = -0.5f - (Mg0z * tx + Mg1z * ty + Mg2z * tz);

        float* r = srec[t];
        r[0] = tx;  r[1] = ty;  r[2] = tz;
        r[3] = qx;  r[4] = qy;  r[5] = qz;  r[6] = qw;
        r[7] = wx;  r[8] = wy;  r[9] = wz;
        r[10] = mx; r[11] = my; r[12] = mz;
        r[13] = Mg0x; r[14] = Mg1x; r[15] = Mg2x;
        r[16] = Mg0y; r[17] = Mg1y; r[18] = Mg2y;
        r[19] = Mg0z; r[20] = Mg1z; r[21] = Mg2z;
        r[22] = Cgx; r[23] = Cgy; r[24] = Cgz;
        r[25] = mx + EPS_G; r[26] = my + EPS_G; r[27] = mz + EPS_G;
        r[28] = mx - EPS_G; r[29] = my - EPS_G; r[30] = mz - EPS_G;
        r[31] = wcx - ex; r[32] = wcy - ey; r[33] = wcz - ez;
        r[34] = wcx + ex; r[35] = wcy + ey; r[36] = wcz + ez;
        int* ri = (int*)r;
        ri[37] = m * sdf_stride;
        ri[38] = SX; ri[39] = SY; ri[40] = SZ;
    }
    __syncthreads();

    // ---- thread -> 8x8 xy lane, wave owns z-half; thread owns 4 z-points ----
    int lane = t & 63;
    int lyy = lane & 7;
    int lxx = lane >> 3;                   // 0..7
    int wz4 = (t >> 6) & 1;                // wave z half: 0 or 1

    int cx = xbk * BXC + lxx;
    int cy = ybk * BYC + lyy;
    int cz0 = zbk * BZC + wz4 * 4;         // multiple of 4

    float px  = GLOWER + ((float)cx + 0.5f) * GSTEP;
    float py  = GLOWER + ((float)cy + 0.5f) * GSTEP;
    float pz0 = GLOWER + ((float)cz0 + 0.5f) * GSTEP;
    float pz1 = GLOWER + ((float)(cz0 + 1) + 0.5f) * GSTEP;
    float pz2 = GLOWER + ((float)(cz0 + 2) + 0.5f) * GSTEP;
    float pz3 = GLOWER + ((float)(cz0 + 3) + 0.5f) * GSTEP;

    size_t out_idx = (size_t)b * PTS_PER_B + ((size_t)cx * GYD + cy) * GZD + cz0;

    // ---- per-wave ballot mask vs the wave's own 8x8x4 cube ----
    float bxl = GLOWER + ((float)(xbk * BXC) + 0.5f) * GSTEP;
    float bxh = GLOWER + ((float)(xbk * BXC + 7) + 0.5f) * GSTEP;
    float byl = GLOWER + ((float)(ybk * BYC) + 0.5f) * GSTEP;
    float byh = GLOWER + ((float)(ybk * BYC + 7) + 0.5f) * GSTEP;
    float bzl = GLOWER + ((float)(zbk * BZC + wz4 * 4) + 0.5f) * GSTEP;
    float bzh = GLOWER + ((float)(zbk * BZC + wz4 * 4 + 3) + 0.5f) * GSTEP;

    bool lok = false;
    if (lane < N) {
        const float* r = srec[lane];
        lok = (bxh >= r[31]) & (bxl <= r[34]) &
              (byh >= r[32]) & (byl <= r[35]) &
              (bzh >= r[33]) & (bzl <= r[36]);
    }
    unsigned int msk = (unsigned int)__ballot(lok);

    if (msk == 0u) {
        *(float4*)(out + out_idx) = make_float4(BIGF, BIGF, BIGF, BIGF);
        return;
    }

    float b0 = BIGF, b1 = BIGF, b2 = BIGF, b3 = BIGF;

    for (int n = 0; n < N; ++n) {
        if (!((msk >> n) & 1u)) continue;  // whole wave certainly outside SDF n

        const float* r = srec[n];

        // affine g at k=0; k=1..3 via increments (drift ~1e-6 << EPS_G;
        // sliver path recomputes the exact reference chain anyway) - r9-validated
        float sgx = fmaf(r[13], px, fmaf(r[14], py, fmaf(r[15], pz0, r[22])));
        float sgy = fmaf(r[16], px, fmaf(r[17], py, fmaf(r[18], pz0, r[23])));
        float sgz = fmaf(r[19], px, fmaf(r[20], py, fmaf(r[21], pz0, r[24])));
        float dgx = GSTEP * r[15];
        float dgy = GSTEP * r[18];
        float dgz = GSTEP * r[21];

        eval_point(r, sdfs, sgx, sgy, sgz, px, py, pz0, b0);
        float s1x = sgx + dgx, s1y = sgy + dgy, s1z = sgz + dgz;
        eval_point(r, sdfs, s1x, s1y, s1z, px, py, pz1, b1);
        float s2x = s1x + dgx, s2y = s1y + dgy, s2z = s1z + dgz;
        eval_point(r, sdfs, s2x, s2y, s2z, px, py, pz2, b2);
        float s3x = s2x + dgx, s3y = s2y + dgy, s3z = s2z + dgz;
        eval_point(r, sdfs, s3x, s3y, s3z, px, py, pz3, b3);
    }

    *(float4*)(out + out_idx) = make_float4(b0, b1, b2, b3);
}

// ---------------- fallback: round-0 validated monolithic kernel ----------------
__global__ __launch_bounds__(256) void sdf_grid_kernel(
    const float* __restrict__ sdfs,
    const int*   __restrict__ sdf_shapes,
    const int*   __restrict__ indices,
    const float* __restrict__ poses,
    const float* __restrict__ widths,
    float*       __restrict__ out,
    int total, int N, int sdf_stride)
{
    int idx = blockIdx.x * blockDim.x + threadIdx.x;
    if (idx >= total) return;
    int z = idx % GZD;
    int y = (idx / GZD) % GYD;
    int x = (idx / (GZD * GYD)) % GXD;
    int b = idx / (GZD * GYD * GXD);
    float px = GLOWER + ((float)x + 0.5f) * GSTEP;
    float py = GLOWER + ((float)y + 0.5f) * GSTEP;
    float pz = GLOWER + ((float)z + 0.5f) * GSTEP;
    float best = BIGF;
    for (int n = 0; n < N; ++n) {
        int bn = b * N + n;
        int m  = indices[bn];
        const float* pp = poses + (size_t)bn * 7;
        float tx = pp[0], ty = pp[1], tz = pp[2];
        float qx = pp[3], qy = pp[4], qz = pp[5], qw = pp[6];
        float nrm = sqrtf(qx * qx + qy * qy + qz * qz + qw * qw);
        qx = qx / nrm; qy = qy / nrm; qz = qz / nrm; qw = qw / nrm;
        float dx = px - tx, dy = py - ty, dz = pz - tz;
        float rx, ry, rz;
        rot_inv(qx, qy, qz, qw, dx, dy, dz, rx, ry, rz);
        const float* ww = widths + (size_t)bn * 3;
        float gx = rx / ww[0] - 0.5f;
        float gy = ry / ww[1] - 0.5f;
        float gz = rz / ww[2] - 0.5f;
        int SX = sdf_shapes[m * 3 + 0];
        int SY = sdf_shapes[m * 3 + 1];
        int SZ = sdf_shapes[m * 3 + 2];
        float mx = (float)(SX - 1), my = (float)(SY - 1), mz = (float)(SZ - 1);
        bool inside = (gx >= 0.0f) && (gx <= mx) &&
                      (gy >= 0.0f) && (gy <= my) &&
                      (gz >= 0.0f) && (gz <= mz);
        float fx = fminf(fmaxf(gx, 0.0f), mx);
        float fy = fminf(fmaxf(gy, 0.0f), my);
        float fz = fminf(fmaxf(gz, 0.0f), mz);
        int i0x = (int)floorf(fx), i0y = (int)floorf(fy), i0z = (int)floorf(fz);
        float frx = fx - (float)i0x, fry = fy - (float)i0y, frz = fz - (float)i0z;
        int i1x = min(i0x + 1, SX - 1);
        int i1y = min(i0y + 1, SY - 1);
        int i1z = min(i0z + 1, SZ - 1);
        const float* sd = sdfs + (size_t)m * sdf_stride;
        int b00 = (i0x * SY + i0y) * SZ;
        int b01 = (i0x * SY + i1y) * SZ;
        int b10 = (i1x * SY + i0y) * SZ;
        int b11 = (i1x * SY + i1y) * SZ;
        float v000 = sd[b00 + i0z], v001 = sd[b00 + i1z];
        float v010 = sd[b01 + i0z], v011 = sd[b01 + i1z];
        float v100 = sd[b10 + i0z], v101 = sd[b10 + i1z];
        float v110 = sd[b11 + i0z], v111 = sd[b11 + i1z];
        float wx0 = 1.0f - frx, wx1 = frx;
        float wy0 = 1.0f - fry, wy1 = fry;
        float wz0 = 1.0f - frz, wz1 = frz;
        float acc = wx0 * wy0 * wz0 * v000 + wx0 * wy0 * wz1 * v001
                  + wx0 * wy1 * wz0 * v010 + wx0 * wy1 * wz1 * v011
                  + wx1 * wy0 * wz0 * v100 + wx1 * wy0 * wz1 * v101
                  + wx1 * wy1 * wz0 * v110 + wx1 * wy1 * wz1 * v111;
        float val = inside ? acc : BIGF;
        best = fminf(best, val);
    }
    out[idx] = best;
}

extern "C" void kernel_launch(void* const* d_in, const int* in_sizes, int n_in,
                              void* d_out, int out_size, void* d_ws, size_t ws_size,
                              hipStream_t stream) {
    const float* sdfs    = (const float*)d_in[0];
    const int*   shapes  = (const int*)d_in[1];
    const int*   indices = (const int*)d_in[2];
    const float* poses   = (const float*)d_in[3];
    const float* widths  = (const float*)d_in[4];
    float*       out     = (float*)d_out;

    int M = in_sizes[1] / 3;           // sdf_shapes is (M,3)
    int sdf_stride = in_sizes[0] / M;  // elements per SDF volume
    int B = out_size / PTS_PER_B;
    int N = in_sizes[2] / B;           // indices is (B,N)

    if (N <= MAXN && (PTS_PER_B % 512) == 0) {
        dim3 grid(BLOCKS_PER_B, B);
        sdf_grid_v11<<<grid, 128, 0, stream>>>(
            sdfs, shapes, indices, poses, widths, out, N, sdf_stride);
    } else {
        int total = out_size;
        int blocks = (total + 255) / 256;
        sdf_grid_kernel<<<blocks, 256, 0, stream>>>(
            sdfs, shapes, indices, poses, widths, out, total, N, sdf_stride);
    }
}